// Round 11
// baseline (511.320 us; speedup 1.0000x reference)
//
#include <hip/hip_runtime.h>
#include <hip/hip_cooperative_groups.h>
#include <math.h>
#include <stdint.h>

namespace cg = cooperative_groups;

#define N_NODES 20000
#define N_EDGES 320000
#define EN_TOT  340000   // E + N (with self loops)
#define CAP     160      // max per-node CSR segment (deg ~ Poisson(16); 160 is >30 sigma)
#define BGRID   1024     // cooperative grid (4 blocks/CU x 256 CU, all resident)

typedef __attribute__((ext_vector_type(8))) _Float16 half8v;  // 8 fp16 (4 VGPRs)
typedef __attribute__((ext_vector_type(2))) _Float16 half2v;  // packed fp16 pair
typedef __attribute__((ext_vector_type(4))) float float4v;    // MFMA accumulator

__device__ __forceinline__ ushort f2h(float f) {              // fp32 -> fp16 RNE
    _Float16 h = (_Float16)f;
    return __builtin_bit_cast(ushort, h);
}
__device__ __forceinline__ float h2f(ushort s) {
    return (float)__builtin_bit_cast(_Float16, s);
}

// online-softmax update / butterfly merge
#define ONL(mm, ss, ll) { float _mn = fmaxf(mm, ll); ss = ss * __expf(mm - _mn) + __expf(ll - _mn); mm = _mn; }
#define MRG(mm, ss, off) { float _mo = __shfl_xor(mm, off), _so = __shfl_xor(ss, off); \
                           float _mn = fmaxf(mm, _mo); ss = ss * __expf(mm - _mn) + _so * __expf(_mo - _mn); mm = _mn; }

// ---------------------------------------------------------------- cooperative build:
// phase1 deg+cursor0 | sync | phase2 scan(block0) || prep+proj(others) | sync | phase3 fill | sync | phase4 loopattr
__global__ __launch_bounds__(256, 4) void k_build(const int* __restrict__ src, const int* __restrict__ dst,
                                                  const float* __restrict__ eattr,
                                                  int* __restrict__ degi, int* __restrict__ cursor,
                                                  int* __restrict__ offsets, int2* __restrict__ csr_se,
                                                  float* __restrict__ loopattr,
                                                  const float* __restrict__ We1, const float* __restrict__ ae1,
                                                  const float* __restrict__ We2, const float* __restrict__ ae2,
                                                  float* __restrict__ M1, float* __restrict__ m2,
                                                  const float* __restrict__ W1, const float* __restrict__ W2,
                                                  const float* __restrict__ Wo, ushort* __restrict__ W1T,
                                                  ushort* __restrict__ W2T, ushort* __restrict__ WoT,
                                                  const float* __restrict__ x, const float* __restrict__ Wp,
                                                  const float* __restrict__ bp, ushort* __restrict__ h0h) {
    cg::grid_group grid = cg::this_grid();
    __shared__ int sc[256];
    int b = blockIdx.x, tid = threadIdx.x;
    int gthreads = BGRID * 256;
    int gt = b * 256 + tid;

    // ---- phase 1: degree count (int2-paired edges) + zero cursor
    for (int e2 = gt; e2 < N_EDGES / 2; e2 += gthreads) {
        int2 d = *(const int2*)&dst[e2 * 2];
        atomicAdd(&degi[d.x], 1);
        atomicAdd(&degi[d.y], 1);
    }
    for (int n = gt; n < N_NODES; n += gthreads) cursor[n] = 0;
    grid.sync();

    // ---- phase 2: block 0 scans; blocks 1.. do weight prep + input proj
    if (b == 0) {
        const int PER = (N_NODES + 255) / 256;   // 79
        int n0 = tid * PER;
        int tot = 0;
        for (int i = 0; i < PER; i++) {
            int n = n0 + i;
            if (n < N_NODES) tot += degi[n] + 1;
        }
        sc[tid] = tot;
        __syncthreads();
        for (int off = 1; off < 256; off <<= 1) {
            int v = (tid >= off) ? sc[tid - off] : 0;
            __syncthreads();
            sc[tid] += v;
            __syncthreads();
        }
        int run = sc[tid] - tot;
        for (int i = 0; i < PER; i++) {
            int n = n0 + i;
            if (n < N_NODES) { offsets[n] = run; run += degi[n] + 1; }
        }
        if (tid == 255) offsets[N_NODES] = sc[255];
        // fold edge-attr projections
        if (tid < 16) {
            int f = tid >> 2, h = tid & 3;
            float acc = 0.f;
            for (int c = 0; c < 128; c++) acc += We1[f * 512 + h * 128 + c] * ae1[h * 128 + c];
            M1[f * 4 + h] = acc;
        } else if (tid < 20) {
            int f = tid - 16;
            float acc = 0.f;
            for (int c = 0; c < 128; c++) acc += We2[f * 128 + c] * ae2[c];
            m2[f] = acc;
        }
    } else {
        int pstride = (BGRID - 1) * 256;
        for (int i = (b - 1) * 256 + tid; i < 2 * 512 * 128 + 128 * 128; i += pstride) {
            if (i < 512 * 128) {
                int nn = i >> 7, kk = i & 127;
                W1T[i] = f2h(W1[kk * 512 + nn]);
            } else if (i < 2 * 512 * 128) {
                int j = i - 512 * 128;
                int nn = j >> 9, kk = j & 511;
                W2T[j] = f2h(W2[kk * 128 + nn]);
            } else {
                int j = i - 2 * 512 * 128;
                int nn = j >> 7, kk = j & 127;
                WoT[j] = f2h(Wo[kk * 128 + nn]);
            }
        }
        int c = tid & 127;
        for (int n = (b - 1) * 2 + (tid >> 7); n < N_NODES; n += (BGRID - 1) * 2) {
            float acc = bp[c];
#pragma unroll
            for (int f = 0; f < 4; f++) acc += x[n * 4 + f] * Wp[f * 128 + c];
            h0h[(size_t)n * 128 + c] = f2h(acc);
        }
    }
    grid.sync();

    // ---- phase 3: CSR fill (packed src,eid)
    for (int i = gt; i < EN_TOT; i += gthreads) {
        int d, sidx, eid;
        if (i < N_EDGES) { d = dst[i]; sidx = src[i]; eid = i; }
        else { int n = i - N_EDGES; d = n; sidx = n; eid = N_EDGES + n; }
        int pos = offsets[d] + atomicAdd(&cursor[d], 1);
        csr_se[pos] = make_int2(sidx, eid);
    }
    grid.sync();

    // ---- phase 4: loop_attr = mean of incoming eattr (1 wave / node)
    int wv = tid >> 6, l = tid & 63;
    for (int n = b * 4 + wv; n < N_NODES; n += BGRID * 4) {
        int startp = offsets[n], endp = offsets[n + 1];
        float sx = 0.f, sy = 0.f, sz = 0.f, sw = 0.f;
        for (int p = startp + l; p < endp; p += 64) {
            int eid = csr_se[p].y;
            if (eid < N_EDGES) {
                float4 e = *(const float4*)&eattr[(size_t)eid * 4];
                sx += e.x; sy += e.y; sz += e.z; sw += e.w;
            }
        }
        for (int off = 32; off; off >>= 1) {
            sx += __shfl_down(sx, off);
            sy += __shfl_down(sy, off);
            sz += __shfl_down(sz, off);
            sw += __shfl_down(sw, off);
        }
        if (l == 0) {
            float inv = 1.0f / fmaxf((float)(endp - startp - 1), 1.0f);
            float4 o;
            o.x = sx * inv; o.y = sy * inv; o.z = sz * inv; o.w = sw * inv;
            *(float4*)&loopattr[(size_t)n * 4] = o;
        }
    }
}

// ---------------------------------------------------------------- MFMA fp16 GEMM + fused row-dot epilogue
// BM x 128 tile (BM = 64 or 32), BK=64, 4 waves each BM x 32, XOR-swizzled LDS.
template<int BM>
__global__ __launch_bounds__(256) void k_gemm_hf(const ushort* __restrict__ A, const ushort* __restrict__ BT,
                                                 float* __restrict__ Cf, ushort* __restrict__ Ch,
                                                 int M, int Nn, int K, const float* __restrict__ bias,
                                                 const float* __restrict__ asv, const float* __restrict__ adv,
                                                 float* __restrict__ outS, float* __restrict__ outD,
                                                 int hstride, const float* __restrict__ sbias) {
    constexpr int MR = BM / 16;
    __shared__ ushort As[BM * 64];
    __shared__ ushort Bs[128 * 64];
    __shared__ float redS[4][BM];
    __shared__ float redD[4][BM];
    const int tid = threadIdx.x;
    const int lane = tid & 63, wid = tid >> 6;
    const int m0 = blockIdx.x * BM, n0 = blockIdx.y * 128;
    float4v acc[MR][2];
#pragma unroll
    for (int i = 0; i < MR; i++)
#pragma unroll
        for (int j = 0; j < 2; j++) acc[i][j] = (float4v){0.f, 0.f, 0.f, 0.f};

    for (int k0 = 0; k0 < K; k0 += 64) {
        __syncthreads();
#pragma unroll
        for (int i = 0; i < BM * 8 / 256; i++) {       // A: BM rows x 8 chunks
            int c = tid + i * 256;
            int row = c >> 3, sl = c & 7;
            int off = row * 128 + ((sl ^ (row & 7)) << 4);
            uint4 va = make_uint4(0u, 0u, 0u, 0u);
            if (m0 + row < M) va = *(const uint4*)&A[(size_t)(m0 + row) * K + k0 + sl * 8];
            *(uint4*)((char*)As + off) = va;
        }
#pragma unroll
        for (int i = 0; i < 4; i++) {                  // B: 128 rows x 8 chunks
            int c = tid + i * 256;
            int row = c >> 3, sl = c & 7;
            int off = row * 128 + ((sl ^ (row & 7)) << 4);
            uint4 vb = *(const uint4*)&BT[(size_t)(n0 + row) * K + k0 + sl * 8];
            *(uint4*)((char*)Bs + off) = vb;
        }
        __syncthreads();
#pragma unroll
        for (int kk = 0; kk < 2; kk++) {
            half8v af[MR], bq[2];
            int sl = kk * 4 + (lane >> 4);
#pragma unroll
            for (int mi = 0; mi < MR; mi++) {
                int row = (lane & 15) + mi * 16;
                af[mi] = *(const half8v*)((const char*)As + row * 128 + ((sl ^ (row & 7)) << 4));
            }
#pragma unroll
            for (int ni = 0; ni < 2; ni++) {
                int row = wid * 32 + ni * 16 + (lane & 15);
                bq[ni] = *(const half8v*)((const char*)Bs + row * 128 + ((sl ^ (row & 7)) << 4));
            }
#pragma unroll
            for (int mi = 0; mi < MR; mi++)
#pragma unroll
                for (int ni = 0; ni < 2; ni++)
                    acc[mi][ni] = __builtin_amdgcn_mfma_f32_16x16x32_f16(af[mi], bq[ni], acc[mi][ni], 0, 0, 0);
        }
    }
    // ---- C write
    float bcol[2];
#pragma unroll
    for (int ni = 0; ni < 2; ni++)
        bcol[ni] = bias ? bias[n0 + wid * 32 + ni * 16 + (lane & 15)] : 0.f;
#pragma unroll
    for (int mi = 0; mi < MR; mi++) {
#pragma unroll
        for (int j = 0; j < 4; j++) {
            int row = m0 + mi * 16 + ((lane >> 4) << 2) + j;
            if (row < M) {
#pragma unroll
                for (int ni = 0; ni < 2; ni++) {
                    int col = n0 + wid * 32 + ni * 16 + (lane & 15);
                    float v = acc[mi][ni][j] + bcol[ni];
                    if (Cf) Cf[(size_t)row * Nn + col] = v;
                    if (Ch) Ch[(size_t)row * Nn + col] = f2h(v);
                }
            }
        }
    }
    // ---- fused row-dot epilogue (als/ald or sigmoid importance)
    if (asv) {
        float asl[2], adl[2];
#pragma unroll
        for (int ni = 0; ni < 2; ni++) {
            int col = n0 + wid * 32 + ni * 16 + (lane & 15);
            asl[ni] = asv[col];
            adl[ni] = adv ? adv[col] : 0.f;
        }
        float psv[MR][4], pdv[MR][4];
#pragma unroll
        for (int mi = 0; mi < MR; mi++)
#pragma unroll
            for (int j = 0; j < 4; j++) {
                float v0 = acc[mi][0][j] + bcol[0];
                float v1 = acc[mi][1][j] + bcol[1];
                psv[mi][j] = v0 * asl[0] + v1 * asl[1];
                pdv[mi][j] = v0 * adl[0] + v1 * adl[1];
            }
#pragma unroll
        for (int off = 1; off < 16; off <<= 1) {
#pragma unroll
            for (int mi = 0; mi < MR; mi++)
#pragma unroll
                for (int j = 0; j < 4; j++) {
                    psv[mi][j] += __shfl_xor(psv[mi][j], off);
                    pdv[mi][j] += __shfl_xor(pdv[mi][j], off);
                }
        }
        if ((lane & 15) == 0) {
#pragma unroll
            for (int mi = 0; mi < MR; mi++)
#pragma unroll
                for (int j = 0; j < 4; j++) {
                    int r = mi * 16 + ((lane >> 4) << 2) + j;
                    redS[wid][r] = psv[mi][j];
                    redD[wid][r] = pdv[mi][j];
                }
        }
        __syncthreads();
        if (tid < BM) {
            int row = m0 + tid;
            if (row < M) {
                float ss = redS[0][tid] + redS[1][tid] + redS[2][tid] + redS[3][tid];
                float dd = redD[0][tid] + redD[1][tid] + redD[2][tid] + redD[3][tid];
                if (sbias) {
                    outS[row] = 1.0f / (1.0f + __expf(-(ss + sbias[0])));
                } else {
                    outS[row * hstride + blockIdx.y] = ss;
                    if (outD) outD[row * hstride + blockIdx.y] = dd;
                }
            }
        }
    }
}

// ---------------------------------------------------------------- layer-1 (R8 champion): fused logits+softmax+gather+LN+ELU
// 128 thr = 2 waves, ONE NODE PER WAVE, zero barriers. Lane owns 8 channels; 8 edges in flight; pk_fma fp16 acc.
__global__ __launch_bounds__(128) void k_agg1(const int* __restrict__ offsets, const int2* __restrict__ csr_se,
                                              const float* __restrict__ eattr, const float* __restrict__ loopattr,
                                              const float* __restrict__ als, const float* __restrict__ aldv,
                                              const float* __restrict__ M1, const ushort* __restrict__ xhh,
                                              const float* __restrict__ b1, const float* __restrict__ g1,
                                              const float* __restrict__ be1, ushort* __restrict__ h1h) {
    int wv = threadIdx.x >> 6, lane = threadIdx.x & 63;
    int n = blockIdx.x * 2 + wv;
    __shared__ float Lc[2][CAP][4];
    __shared__ int   sSrc[2][CAP];
    __shared__ float mhs[2][4], shs[2][4];

    int start = offsets[n];
    int cnt = min(offsets[n + 1] - start, CAP);

    // ---- phase A: inline logits + online softmax stats (4 lanes per edge)
    int hh = lane & 3;
    float aldn = aldv[n * 4 + hh];
    float c0 = M1[hh], c1 = M1[4 + hh], c2 = M1[8 + hh], c3 = M1[12 + hh];
    float m = -1e30f, s = 0.f;
    for (int j = lane >> 2; j < cnt; j += 16) {
        int2 se = csr_se[start + j];
        const float* eap = (se.y < N_EDGES) ? &eattr[(size_t)se.y * 4] : &loopattr[(size_t)(se.y - N_EDGES) * 4];
        float4 e4 = *(const float4*)eap;
        float l = als[se.x * 4 + hh] + aldn + e4.x * c0 + e4.y * c1 + e4.z * c2 + e4.w * c3;
        l = (l >= 0.f) ? l : 0.2f * l;
        Lc[wv][j][hh] = l;
        if (hh == 0) sSrc[wv][j] = se.x;
        ONL(m, s, l);
    }
#pragma unroll
    for (int off = 4; off < 64; off <<= 1) { MRG(m, s, off); }
    if (lane < 4) { mhs[wv][lane] = m; shs[wv][lane] = 1.0f / s; }
    // wave-internal LDS ordering: no barrier needed (per-wave slices)

    // ---- phase A2: logits -> alpha in place
    int tot = cnt * 4;
    for (int idx = lane; idx < tot; idx += 64) {
        int j = idx >> 2, h = idx & 3;
        Lc[wv][j][h] = __expf(Lc[wv][j][h] - mhs[wv][h]) * shs[wv][h];
    }

    // ---- gather: lane owns channels 8*lane..8*lane+7; 8 edges in flight; fp16 packed accumulate
    half2v hac0 = (half2v)0, hac1 = (half2v)0, hac2 = (half2v)0, hac3 = (half2v)0;
    int hg = lane >> 4;
    uint ch = (uint)lane * 8u;
    int j = 0;
    for (; j + 8 <= cnt; j += 8) {
        _Float16 av[8];
        uint4 vv[8];
#pragma unroll
        for (int t = 0; t < 8; t++) av[t] = (_Float16)Lc[wv][j + t][hg];
#pragma unroll
        for (int t = 0; t < 8; t++) vv[t] = *(const uint4*)&xhh[((uint)sSrc[wv][j + t] << 9) + ch];
#pragma unroll
        for (int t = 0; t < 8; t++) {
            half2v a2 = (half2v){av[t], av[t]};
            const half2v* pv = (const half2v*)&vv[t];
            hac0 = pv[0] * a2 + hac0;
            hac1 = pv[1] * a2 + hac1;
            hac2 = pv[2] * a2 + hac2;
            hac3 = pv[3] * a2 + hac3;
        }
    }
    for (; j < cnt; j++) {
        _Float16 a = (_Float16)Lc[wv][j][hg];
        half2v a2 = (half2v){a, a};
        uint4 v = *(const uint4*)&xhh[((uint)sSrc[wv][j] << 9) + ch];
        const half2v* pv = (const half2v*)&v;
        hac0 = pv[0] * a2 + hac0;
        hac1 = pv[1] * a2 + hac1;
        hac2 = pv[2] * a2 + hac2;
        hac3 = pv[3] * a2 + hac3;
    }

    // ---- + bias, LayerNorm(512), ELU — wave-local shuffles
    float4 ba = *(const float4*)&b1[ch];
    float4 bb = *(const float4*)&b1[ch + 4];
    float v0 = (float)hac0[0] + ba.x, v1 = (float)hac0[1] + ba.y;
    float v2 = (float)hac1[0] + ba.z, v3 = (float)hac1[1] + ba.w;
    float v4 = (float)hac2[0] + bb.x, v5 = (float)hac2[1] + bb.y;
    float v6 = (float)hac3[0] + bb.z, v7 = (float)hac3[1] + bb.w;
    float s8 = v0 + v1 + v2 + v3 + v4 + v5 + v6 + v7;
#pragma unroll
    for (int off = 1; off < 64; off <<= 1) s8 += __shfl_xor(s8, off);
    float mu = s8 * (1.0f / 512.0f);
    float d0 = v0 - mu, d1 = v1 - mu, d2 = v2 - mu, d3 = v3 - mu;
    float d4 = v4 - mu, d5 = v5 - mu, d6 = v6 - mu, d7 = v7 - mu;
    float sq = d0 * d0 + d1 * d1 + d2 * d2 + d3 * d3 + d4 * d4 + d5 * d5 + d6 * d6 + d7 * d7;
#pragma unroll
    for (int off = 1; off < 64; off <<= 1) sq += __shfl_xor(sq, off);
    float rstd = rsqrtf(sq * (1.0f / 512.0f) + 1e-5f);
    float4 ga = *(const float4*)&g1[ch];
    float4 gb = *(const float4*)&g1[ch + 4];
    float4 ea = *(const float4*)&be1[ch];
    float4 eb = *(const float4*)&be1[ch + 4];
    float y0 = d0 * rstd * ga.x + ea.x, y1 = d1 * rstd * ga.y + ea.y;
    float y2 = d2 * rstd * ga.z + ea.z, y3 = d3 * rstd * ga.w + ea.w;
    float y4 = d4 * rstd * gb.x + eb.x, y5 = d5 * rstd * gb.y + eb.y;
    float y6 = d6 * rstd * gb.z + eb.z, y7 = d7 * rstd * gb.w + eb.w;
    y0 = (y0 > 0.f) ? y0 : (__expf(y0) - 1.0f);
    y1 = (y1 > 0.f) ? y1 : (__expf(y1) - 1.0f);
    y2 = (y2 > 0.f) ? y2 : (__expf(y2) - 1.0f);
    y3 = (y3 > 0.f) ? y3 : (__expf(y3) - 1.0f);
    y4 = (y4 > 0.f) ? y4 : (__expf(y4) - 1.0f);
    y5 = (y5 > 0.f) ? y5 : (__expf(y5) - 1.0f);
    y6 = (y6 > 0.f) ? y6 : (__expf(y6) - 1.0f);
    y7 = (y7 > 0.f) ? y7 : (__expf(y7) - 1.0f);
    uint4 o;
    o.x = (uint)f2h(y0) | ((uint)f2h(y1) << 16);
    o.y = (uint)f2h(y2) | ((uint)f2h(y3) << 16);
    o.z = (uint)f2h(y4) | ((uint)f2h(y5) << 16);
    o.w = (uint)f2h(y6) | ((uint)f2h(y7) << 16);
    *(uint4*)&h1h[(size_t)n * 512 + ch] = o;
}

// ---------------------------------------------------------------- layer-2 (R8): fused logits+softmax+alpha-out+gather+LN
__global__ __launch_bounds__(128) void k_agg2(const int* __restrict__ offsets, const int2* __restrict__ csr_se,
                                              const float* __restrict__ eattr, const float* __restrict__ loopattr,
                                              const float* __restrict__ als, const float* __restrict__ aldv,
                                              const float* __restrict__ m2v, const ushort* __restrict__ xh2h,
                                              const float* __restrict__ b2, const float* __restrict__ g2,
                                              const float* __restrict__ be2, float* __restrict__ eaout,
                                              ushort* __restrict__ h2h) {
    int wv = threadIdx.x >> 6, lane = threadIdx.x & 63;
    int n = blockIdx.x * 2 + wv;
    __shared__ float Lc[2][CAP];
    __shared__ int   sS[2][CAP];
    __shared__ int   sE[2][CAP];

    int start = offsets[n];
    int cnt = min(offsets[n + 1] - start, CAP);
    float aldn = aldv[n];
    float c0 = m2v[0], c1 = m2v[1], c2 = m2v[2], c3 = m2v[3];
    float m = -1e30f, s = 0.f;
    for (int j = lane; j < cnt; j += 64) {
        int2 se = csr_se[start + j];
        const float* eap = (se.y < N_EDGES) ? &eattr[(size_t)se.y * 4] : &loopattr[(size_t)(se.y - N_EDGES) * 4];
        float4 e4 = *(const float4*)eap;
        float l = als[se.x] + aldn + e4.x * c0 + e4.y * c1 + e4.z * c2 + e4.w * c3;
        l = (l >= 0.f) ? l : 0.2f * l;
        Lc[wv][j] = l; sS[wv][j] = se.x; sE[wv][j] = se.y;
        ONL(m, s, l);
    }
#pragma unroll
    for (int off = 1; off < 64; off <<= 1) { MRG(m, s, off); }
    float inv = 1.0f / s;
    for (int j = lane; j < cnt; j += 64) {
        float a = __expf(Lc[wv][j] - m) * inv;
        Lc[wv][j] = a;
        eaout[sE[wv][j]] = a;
    }
    // gather: lane owns channels 2*lane, 2*lane+1; 8 edges in flight; fp16 packed accumulate
    half2v hac = (half2v)0;
    uint ch = (uint)lane * 2u;
    int j = 0;
    for (; j + 8 <= cnt; j += 8) {
        _Float16 av[8];
        uint vv[8];
#pragma unroll
        for (int tt = 0; tt < 8; tt++) av[tt] = (_Float16)Lc[wv][j + tt];
#pragma unroll
        for (int tt = 0; tt < 8; tt++) vv[tt] = *(const uint*)&xh2h[((uint)sS[wv][j + tt] << 7) + ch];
#pragma unroll
        for (int tt = 0; tt < 8; tt++) {
            half2v a2 = (half2v){av[tt], av[tt]};
            half2v pv = __builtin_bit_cast(half2v, vv[tt]);
            hac = pv * a2 + hac;
        }
    }
    for (; j < cnt; j++) {
        _Float16 a = (_Float16)Lc[wv][j];
        half2v a2 = (half2v){a, a};
        half2v pv = __builtin_bit_cast(half2v, *(const uint*)&xh2h[((uint)sS[wv][j] << 7) + ch]);
        hac = pv * a2 + hac;
    }
    // bias + LN(128) within the wave
    float2 bb = *(const float2*)&b2[ch];
    float v0 = (float)hac[0] + bb.x, v1 = (float)hac[1] + bb.y;
    float s2 = v0 + v1;
#pragma unroll
    for (int off = 1; off < 64; off <<= 1) s2 += __shfl_xor(s2, off);
    float mu = s2 * (1.0f / 128.0f);
    float d0 = v0 - mu, d1 = v1 - mu;
    float q = d0 * d0 + d1 * d1;
#pragma unroll
    for (int off = 1; off < 64; off <<= 1) q += __shfl_xor(q, off);
    float rstd = rsqrtf(q * (1.0f / 128.0f) + 1e-5f);
    float2 gg = *(const float2*)&g2[ch];
    float2 ee = *(const float2*)&be2[ch];
    float y0 = d0 * rstd * gg.x + ee.x;
    float y1 = d1 * rstd * gg.y + ee.y;
    uint o = (uint)f2h(y0) | ((uint)f2h(y1) << 16);
    *(uint*)&h2h[(size_t)n * 128 + ch] = o;
}

// ================================================================ launch
extern "C" void kernel_launch(void* const* d_in, const int* in_sizes, int n_in,
                              void* d_out, int out_size, void* d_ws, size_t ws_size,
                              hipStream_t stream) {
    const float* x    = (const float*)d_in[0];
    const int*   eidx = (const int*)d_in[1];
    const float* eattr= (const float*)d_in[2];
    const float* Wp   = (const float*)d_in[3];
    const float* bp   = (const float*)d_in[4];
    const float* W1   = (const float*)d_in[5];
    const float* We1  = (const float*)d_in[6];
    const float* as1  = (const float*)d_in[7];
    const float* ad1  = (const float*)d_in[8];
    const float* ae1  = (const float*)d_in[9];
    const float* b1   = (const float*)d_in[10];
    const float* g1   = (const float*)d_in[11];
    const float* be1  = (const float*)d_in[12];
    const float* W2   = (const float*)d_in[13];
    const float* We2  = (const float*)d_in[14];
    const float* as2  = (const float*)d_in[15];
    const float* ad2  = (const float*)d_in[16];
    const float* ae2  = (const float*)d_in[17];
    const float* b2   = (const float*)d_in[18];
    const float* g2   = (const float*)d_in[19];
    const float* be2  = (const float*)d_in[20];
    const float* Wo   = (const float*)d_in[21];
    const float* bo   = (const float*)d_in[22];
    const float* Wi   = (const float*)d_in[23];
    const float* bi   = (const float*)d_in[24];

    const int* src = eidx;
    const int* dst = eidx + N_EDGES;

    float* emb_out = (float*)d_out;                       // [N,128]
    float* ea_out  = emb_out + (size_t)N_NODES * 128;     // [E+N]
    float* imp_out = ea_out + EN_TOT;                     // [N]

    // ---- workspace carve (256B aligned) ----
    char* w = (char*)d_ws;
    auto alloc = [&](size_t bytes) -> void* { void* p = (void*)w; w += (bytes + 255) & ~(size_t)255; return p; };
    ushort* xhh    = (ushort*)alloc((size_t)N_NODES * 512 * 2);  // [N,512] fp16
    ushort* h1h    = (ushort*)alloc((size_t)N_NODES * 512 * 2);  // [N,512] fp16
    ushort* h0h    = (ushort*)alloc((size_t)N_NODES * 128 * 2);  // [N,128] fp16
    ushort* xh2h   = (ushort*)alloc((size_t)N_NODES * 128 * 2);  // [N,128] fp16
    ushort* h2h    = (ushort*)alloc((size_t)N_NODES * 128 * 2);  // [N,128] fp16
    ushort* W1T    = (ushort*)alloc((size_t)512 * 128 * 2);
    ushort* W2T    = (ushort*)alloc((size_t)128 * 512 * 2);
    ushort* WoT    = (ushort*)alloc((size_t)128 * 128 * 2);
    int2*  csr_se  = (int2*)alloc((size_t)EN_TOT * 8);
    int*   offsets = (int*)alloc((size_t)(N_NODES + 1) * 4);
    int*   cursor  = (int*)alloc((size_t)N_NODES * 4);
    int*   degi    = (int*)alloc((size_t)N_NODES * 4);
    float* loopat  = (float*)alloc((size_t)N_NODES * 4 * 4);
    float* als1v   = (float*)alloc((size_t)N_NODES * 4 * 4);
    float* ald1v   = (float*)alloc((size_t)N_NODES * 4 * 4);
    float* als2v   = (float*)alloc((size_t)N_NODES * 4);
    float* ald2v   = (float*)alloc((size_t)N_NODES * 4);
    float* M1      = (float*)alloc(32 * 4);
    float* m2      = M1 + 16;

    hipMemsetAsync(degi, 0, (size_t)N_NODES * 4, stream);

    // ---- cooperative build: deg | scan + prep/proj | fill | loopattr
    {
        void* kargs[] = {
            (void*)&src, (void*)&dst, (void*)&eattr,
            (void*)&degi, (void*)&cursor, (void*)&offsets, (void*)&csr_se, (void*)&loopat,
            (void*)&We1, (void*)&ae1, (void*)&We2, (void*)&ae2, (void*)&M1, (void*)&m2,
            (void*)&W1, (void*)&W2, (void*)&Wo, (void*)&W1T, (void*)&W2T, (void*)&WoT,
            (void*)&x, (void*)&Wp, (void*)&bp, (void*)&h0h
        };
        hipLaunchCooperativeKernel((const void*)k_build, dim3(BGRID), dim3(256), kargs, 0, stream);
    }

    // xh = h0 @ W1  + fused als1/ald1 (blockIdx.y == head)
    k_gemm_hf<64><<<dim3((N_NODES + 63) / 64, 4), 256, 0, stream>>>(h0h, W1T, nullptr, xhh,
                                                                    N_NODES, 512, 128, nullptr,
                                                                    as1, ad1, als1v, ald1v, 4, nullptr);
    k_agg1<<<N_NODES / 2, 128, 0, stream>>>(offsets, csr_se, eattr, loopat, als1v, ald1v, M1,
                                            xhh, b1, g1, be1, h1h);

    // xh2 = h1 @ W2  + fused als2/ald2  (BM=32 -> 625 blocks)
    k_gemm_hf<32><<<dim3((N_NODES + 31) / 32, 1), 256, 0, stream>>>(h1h, W2T, nullptr, xh2h,
                                                                    N_NODES, 128, 512, nullptr,
                                                                    as2, ad2, als2v, ald2v, 1, nullptr);
    k_agg2<<<N_NODES / 2, 128, 0, stream>>>(offsets, csr_se, eattr, loopat, als2v, ald2v, m2,
                                            xh2h, b2, g2, be2, ea_out, h2h);

    // emb = h2 @ Wo + bo -> d_out (fp32) + fused importance (sigmoid(emb@Wi+bi))
    k_gemm_hf<32><<<dim3((N_NODES + 31) / 32, 1), 256, 0, stream>>>(h2h, WoT, emb_out, nullptr,
                                                                    N_NODES, 128, 128, bo,
                                                                    Wi, nullptr, imp_out, nullptr, 1, bi);
}

// Round 12
// 202.221 us; speedup vs baseline: 2.5285x; 2.5285x over previous
//
#include <hip/hip_runtime.h>
#include <math.h>
#include <stdint.h>

#define N_NODES 20000
#define N_EDGES 320000
#define EN_TOT  340000   // E + N (with self loops)
#define CAP     160      // max per-node CSR segment (deg ~ Poisson(16); 160 is >30 sigma)

typedef __attribute__((ext_vector_type(8))) _Float16 half8v;  // 8 fp16 (4 VGPRs)
typedef __attribute__((ext_vector_type(2))) _Float16 half2v;  // packed fp16 pair
typedef __attribute__((ext_vector_type(4))) float float4v;    // MFMA accumulator

__device__ __forceinline__ ushort f2h(float f) {              // fp32 -> fp16 RNE
    _Float16 h = (_Float16)f;
    return __builtin_bit_cast(ushort, h);
}
__device__ __forceinline__ float h2f(ushort s) {
    return (float)__builtin_bit_cast(_Float16, s);
}

// online-softmax update / butterfly merge
#define ONL(mm, ss, ll) { float _mn = fmaxf(mm, ll); ss = ss * __expf(mm - _mn) + __expf(ll - _mn); mm = _mn; }
#define MRG(mm, ss, off) { float _mo = __shfl_xor(mm, off), _so = __shfl_xor(ss, off); \
                           float _mn = fmaxf(mm, _mo); ss = ss * __expf(mm - _mn) + _so * __expf(_mo - _mn); mm = _mn; }

// ---------------------------------------------------------------- degree count (1 int atomic / edge, int2 loads)
__global__ void k_deg(const int* __restrict__ dst, int* __restrict__ degi) {
    int e = (blockIdx.x * 256 + threadIdx.x) * 2;
    if (e >= N_EDGES) return;
    int2 d = *(const int2*)&dst[e];
    atomicAdd(&degi[d.x], 1);
    atomicAdd(&degi[d.y], 1);
}

// ---------------------------------------------------------------- scan (offsets) + M1/m2 fold
__global__ __launch_bounds__(1024) void k_scan(const int* __restrict__ degi, int* __restrict__ offsets,
                                               const float* __restrict__ We1, const float* __restrict__ ae1,
                                               const float* __restrict__ We2, const float* __restrict__ ae2,
                                               float* __restrict__ M1, float* __restrict__ m2) {
    __shared__ int s[1024];
    int t = threadIdx.x;
    int n0 = t * 20;
    int tot = 0;
    for (int i = 0; i < 20; i++) {
        int n = n0 + i;
        if (n < N_NODES) tot += degi[n] + 1;
    }
    s[t] = tot;
    __syncthreads();
    for (int off = 1; off < 1024; off <<= 1) {
        int v = (t >= off) ? s[t - off] : 0;
        __syncthreads();
        s[t] += v;
        __syncthreads();
    }
    int run = s[t] - tot;
    for (int i = 0; i < 20; i++) {
        int n = n0 + i;
        if (n < N_NODES) {
            offsets[n] = run;
            run += degi[n] + 1;
        }
    }
    if (t == 1023) offsets[N_NODES] = s[1023];
    if (t < 16) {
        int f = t >> 2, h = t & 3;
        float acc = 0.f;
        for (int c = 0; c < 128; c++) acc += We1[f * 512 + h * 128 + c] * ae1[h * 128 + c];
        M1[f * 4 + h] = acc;
    } else if (t < 20) {
        int f = t - 16;
        float acc = 0.f;
        for (int c = 0; c < 128; c++) acc += We2[f * 128 + c] * ae2[c];
        m2[f] = acc;
    }
}

// ---------------------------------------------------------------- CSR fill: packed (src, eid) int2
__global__ void k_fill(const int* __restrict__ src, const int* __restrict__ dst,
                       const int* __restrict__ offsets, int* __restrict__ cursor,
                       int2* __restrict__ csr_se) {
    int i = blockIdx.x * 256 + threadIdx.x;
    if (i >= EN_TOT) return;
    int d, sidx, eid;
    if (i < N_EDGES) { d = dst[i]; sidx = src[i]; eid = i; }
    else { int n = i - N_EDGES; d = n; sidx = n; eid = N_EDGES + n; }
    int pos = offsets[d] + atomicAdd(&cursor[d], 1);
    csr_se[pos] = make_int2(sidx, eid);
}

// ---------------------------------------------------------------- merged: loop_attr | weight prep | input proj
__global__ __launch_bounds__(256) void k_misc(const int* __restrict__ offsets, const int2* __restrict__ csr_se,
                                              const float* __restrict__ eattr, float* __restrict__ loopattr,
                                              const float* __restrict__ W1, const float* __restrict__ W2,
                                              const float* __restrict__ Wo, ushort* __restrict__ W1T,
                                              ushort* __restrict__ W2T, ushort* __restrict__ WoT,
                                              const float* __restrict__ x, const float* __restrict__ Wp,
                                              const float* __restrict__ bp, ushort* __restrict__ h0h) {
    int b = blockIdx.x;
    int tid = threadIdx.x;
    if (b < 5000) {
        int wv = tid >> 6, l = tid & 63;
        int n = b * 4 + wv;
        if (n >= N_NODES) return;
        int start = offsets[n], end = offsets[n + 1];
        float sx = 0.f, sy = 0.f, sz = 0.f, sw = 0.f;
        for (int p = start + l; p < end; p += 64) {
            int eid = csr_se[p].y;
            if (eid < N_EDGES) {
                float4 e = *(const float4*)&eattr[(size_t)eid * 4];
                sx += e.x; sy += e.y; sz += e.z; sw += e.w;
            }
        }
        for (int off = 32; off; off >>= 1) {
            sx += __shfl_down(sx, off);
            sy += __shfl_down(sy, off);
            sz += __shfl_down(sz, off);
            sw += __shfl_down(sw, off);
        }
        if (l == 0) {
            float inv = 1.0f / fmaxf((float)(end - start - 1), 1.0f);
            float4 o;
            o.x = sx * inv; o.y = sy * inv; o.z = sz * inv; o.w = sw * inv;
            *(float4*)&loopattr[(size_t)n * 4] = o;
        }
    } else if (b < 5576) {
        int i = (b - 5000) * 256 + tid;
        if (i < 512 * 128) {
            int nn = i >> 7, kk = i & 127;
            W1T[i] = f2h(W1[kk * 512 + nn]);
        } else if (i < 2 * 512 * 128) {
            int j = i - 512 * 128;
            int nn = j >> 9, kk = j & 511;
            W2T[j] = f2h(W2[kk * 128 + nn]);
        } else if (i < 2 * 512 * 128 + 128 * 128) {
            int j = i - 2 * 512 * 128;
            int nn = j >> 7, kk = j & 127;
            WoT[j] = f2h(Wo[kk * 128 + nn]);
        }
    } else {
        int n = (b - 5576) * 2 + (tid >> 7);
        int c = tid & 127;
        float acc = bp[c];
#pragma unroll
        for (int f = 0; f < 4; f++) acc += x[n * 4 + f] * Wp[f * 128 + c];
        h0h[(size_t)n * 128 + c] = f2h(acc);
    }
}

// ---------------------------------------------------------------- MFMA fp16 GEMM + fused row-dot epilogue
// BM x 128 tile (BM = 64 or 32), BK=64, 4 waves each BM x 32, XOR-swizzled LDS.
template<int BM>
__global__ __launch_bounds__(256) void k_gemm_hf(const ushort* __restrict__ A, const ushort* __restrict__ BT,
                                                 float* __restrict__ Cf, ushort* __restrict__ Ch,
                                                 int M, int Nn, int K, const float* __restrict__ bias,
                                                 const float* __restrict__ asv, const float* __restrict__ adv,
                                                 float* __restrict__ outS, float* __restrict__ outD,
                                                 int hstride, const float* __restrict__ sbias) {
    constexpr int MR = BM / 16;
    __shared__ ushort As[BM * 64];
    __shared__ ushort Bs[128 * 64];
    __shared__ float redS[4][BM];
    __shared__ float redD[4][BM];
    const int tid = threadIdx.x;
    const int lane = tid & 63, wid = tid >> 6;
    const int m0 = blockIdx.x * BM, n0 = blockIdx.y * 128;
    float4v acc[MR][2];
#pragma unroll
    for (int i = 0; i < MR; i++)
#pragma unroll
        for (int j = 0; j < 2; j++) acc[i][j] = (float4v){0.f, 0.f, 0.f, 0.f};

    for (int k0 = 0; k0 < K; k0 += 64) {
        __syncthreads();
#pragma unroll
        for (int i = 0; i < BM * 8 / 256; i++) {       // A: BM rows x 8 chunks
            int c = tid + i * 256;
            int row = c >> 3, sl = c & 7;
            int off = row * 128 + ((sl ^ (row & 7)) << 4);
            uint4 va = make_uint4(0u, 0u, 0u, 0u);
            if (m0 + row < M) va = *(const uint4*)&A[(size_t)(m0 + row) * K + k0 + sl * 8];
            *(uint4*)((char*)As + off) = va;
        }
#pragma unroll
        for (int i = 0; i < 4; i++) {                  // B: 128 rows x 8 chunks
            int c = tid + i * 256;
            int row = c >> 3, sl = c & 7;
            int off = row * 128 + ((sl ^ (row & 7)) << 4);
            uint4 vb = *(const uint4*)&BT[(size_t)(n0 + row) * K + k0 + sl * 8];
            *(uint4*)((char*)Bs + off) = vb;
        }
        __syncthreads();
#pragma unroll
        for (int kk = 0; kk < 2; kk++) {
            half8v af[MR], bq[2];
            int sl = kk * 4 + (lane >> 4);
#pragma unroll
            for (int mi = 0; mi < MR; mi++) {
                int row = (lane & 15) + mi * 16;
                af[mi] = *(const half8v*)((const char*)As + row * 128 + ((sl ^ (row & 7)) << 4));
            }
#pragma unroll
            for (int ni = 0; ni < 2; ni++) {
                int row = wid * 32 + ni * 16 + (lane & 15);
                bq[ni] = *(const half8v*)((const char*)Bs + row * 128 + ((sl ^ (row & 7)) << 4));
            }
#pragma unroll
            for (int mi = 0; mi < MR; mi++)
#pragma unroll
                for (int ni = 0; ni < 2; ni++)
                    acc[mi][ni] = __builtin_amdgcn_mfma_f32_16x16x32_f16(af[mi], bq[ni], acc[mi][ni], 0, 0, 0);
        }
    }
    // ---- C write
    float bcol[2];
#pragma unroll
    for (int ni = 0; ni < 2; ni++)
        bcol[ni] = bias ? bias[n0 + wid * 32 + ni * 16 + (lane & 15)] : 0.f;
#pragma unroll
    for (int mi = 0; mi < MR; mi++) {
#pragma unroll
        for (int j = 0; j < 4; j++) {
            int row = m0 + mi * 16 + ((lane >> 4) << 2) + j;
            if (row < M) {
#pragma unroll
                for (int ni = 0; ni < 2; ni++) {
                    int col = n0 + wid * 32 + ni * 16 + (lane & 15);
                    float v = acc[mi][ni][j] + bcol[ni];
                    if (Cf) Cf[(size_t)row * Nn + col] = v;
                    if (Ch) Ch[(size_t)row * Nn + col] = f2h(v);
                }
            }
        }
    }
    // ---- fused row-dot epilogue (als/ald or sigmoid importance)
    if (asv) {
        float asl[2], adl[2];
#pragma unroll
        for (int ni = 0; ni < 2; ni++) {
            int col = n0 + wid * 32 + ni * 16 + (lane & 15);
            asl[ni] = asv[col];
            adl[ni] = adv ? adv[col] : 0.f;
        }
        float psv[MR][4], pdv[MR][4];
#pragma unroll
        for (int mi = 0; mi < MR; mi++)
#pragma unroll
            for (int j = 0; j < 4; j++) {
                float v0 = acc[mi][0][j] + bcol[0];
                float v1 = acc[mi][1][j] + bcol[1];
                psv[mi][j] = v0 * asl[0] + v1 * asl[1];
                pdv[mi][j] = v0 * adl[0] + v1 * adl[1];
            }
#pragma unroll
        for (int off = 1; off < 16; off <<= 1) {
#pragma unroll
            for (int mi = 0; mi < MR; mi++)
#pragma unroll
                for (int j = 0; j < 4; j++) {
                    psv[mi][j] += __shfl_xor(psv[mi][j], off);
                    pdv[mi][j] += __shfl_xor(pdv[mi][j], off);
                }
        }
        if ((lane & 15) == 0) {
#pragma unroll
            for (int mi = 0; mi < MR; mi++)
#pragma unroll
                for (int j = 0; j < 4; j++) {
                    int r = mi * 16 + ((lane >> 4) << 2) + j;
                    redS[wid][r] = psv[mi][j];
                    redD[wid][r] = pdv[mi][j];
                }
        }
        __syncthreads();
        if (tid < BM) {
            int row = m0 + tid;
            if (row < M) {
                float ss = redS[0][tid] + redS[1][tid] + redS[2][tid] + redS[3][tid];
                float dd = redD[0][tid] + redD[1][tid] + redD[2][tid] + redD[3][tid];
                if (sbias) {
                    outS[row] = 1.0f / (1.0f + __expf(-(ss + sbias[0])));
                } else {
                    outS[row * hstride + blockIdx.y] = ss;
                    if (outD) outD[row * hstride + blockIdx.y] = dd;
                }
            }
        }
    }
}

// ---------------------------------------------------------------- layer-1 (R8 champion): fused logits+softmax+gather+LN+ELU
// 128 thr = 2 waves, ONE NODE PER WAVE, zero barriers. Lane owns 8 channels; 8 edges in flight; pk_fma fp16 acc.
__global__ __launch_bounds__(128) void k_agg1(const int* __restrict__ offsets, const int2* __restrict__ csr_se,
                                              const float* __restrict__ eattr, const float* __restrict__ loopattr,
                                              const float* __restrict__ als, const float* __restrict__ aldv,
                                              const float* __restrict__ M1, const ushort* __restrict__ xhh,
                                              const float* __restrict__ b1, const float* __restrict__ g1,
                                              const float* __restrict__ be1, ushort* __restrict__ h1h) {
    int wv = threadIdx.x >> 6, lane = threadIdx.x & 63;
    int n = blockIdx.x * 2 + wv;
    __shared__ float Lc[2][CAP][4];
    __shared__ int   sSrc[2][CAP];
    __shared__ float mhs[2][4], shs[2][4];

    int start = offsets[n];
    int cnt = min(offsets[n + 1] - start, CAP);

    // ---- phase A: inline logits + online softmax stats (4 lanes per edge)
    int hh = lane & 3;
    float aldn = aldv[n * 4 + hh];
    float c0 = M1[hh], c1 = M1[4 + hh], c2 = M1[8 + hh], c3 = M1[12 + hh];
    float m = -1e30f, s = 0.f;
    for (int j = lane >> 2; j < cnt; j += 16) {
        int2 se = csr_se[start + j];
        const float* eap = (se.y < N_EDGES) ? &eattr[(size_t)se.y * 4] : &loopattr[(size_t)(se.y - N_EDGES) * 4];
        float4 e4 = *(const float4*)eap;
        float l = als[se.x * 4 + hh] + aldn + e4.x * c0 + e4.y * c1 + e4.z * c2 + e4.w * c3;
        l = (l >= 0.f) ? l : 0.2f * l;
        Lc[wv][j][hh] = l;
        if (hh == 0) sSrc[wv][j] = se.x;
        ONL(m, s, l);
    }
#pragma unroll
    for (int off = 4; off < 64; off <<= 1) { MRG(m, s, off); }
    if (lane < 4) { mhs[wv][lane] = m; shs[wv][lane] = 1.0f / s; }
    // wave-internal LDS ordering: no barrier needed (per-wave slices)

    // ---- phase A2: logits -> alpha in place
    int tot = cnt * 4;
    for (int idx = lane; idx < tot; idx += 64) {
        int j = idx >> 2, h = idx & 3;
        Lc[wv][j][h] = __expf(Lc[wv][j][h] - mhs[wv][h]) * shs[wv][h];
    }

    // ---- gather: lane owns channels 8*lane..8*lane+7; 8 edges in flight; fp16 packed accumulate
    half2v hac0 = (half2v)0, hac1 = (half2v)0, hac2 = (half2v)0, hac3 = (half2v)0;
    int hg = lane >> 4;
    uint ch = (uint)lane * 8u;
    int j = 0;
    for (; j + 8 <= cnt; j += 8) {
        _Float16 av[8];
        uint4 vv[8];
#pragma unroll
        for (int t = 0; t < 8; t++) av[t] = (_Float16)Lc[wv][j + t][hg];
#pragma unroll
        for (int t = 0; t < 8; t++) vv[t] = *(const uint4*)&xhh[((uint)sSrc[wv][j + t] << 9) + ch];
#pragma unroll
        for (int t = 0; t < 8; t++) {
            half2v a2 = (half2v){av[t], av[t]};
            const half2v* pv = (const half2v*)&vv[t];
            hac0 = pv[0] * a2 + hac0;
            hac1 = pv[1] * a2 + hac1;
            hac2 = pv[2] * a2 + hac2;
            hac3 = pv[3] * a2 + hac3;
        }
    }
    for (; j < cnt; j++) {
        _Float16 a = (_Float16)Lc[wv][j][hg];
        half2v a2 = (half2v){a, a};
        uint4 v = *(const uint4*)&xhh[((uint)sSrc[wv][j] << 9) + ch];
        const half2v* pv = (const half2v*)&v;
        hac0 = pv[0] * a2 + hac0;
        hac1 = pv[1] * a2 + hac1;
        hac2 = pv[2] * a2 + hac2;
        hac3 = pv[3] * a2 + hac3;
    }

    // ---- + bias, LayerNorm(512), ELU — wave-local shuffles
    float4 ba = *(const float4*)&b1[ch];
    float4 bb = *(const float4*)&b1[ch + 4];
    float v0 = (float)hac0[0] + ba.x, v1 = (float)hac0[1] + ba.y;
    float v2 = (float)hac1[0] + ba.z, v3 = (float)hac1[1] + ba.w;
    float v4 = (float)hac2[0] + bb.x, v5 = (float)hac2[1] + bb.y;
    float v6 = (float)hac3[0] + bb.z, v7 = (float)hac3[1] + bb.w;
    float s8 = v0 + v1 + v2 + v3 + v4 + v5 + v6 + v7;
#pragma unroll
    for (int off = 1; off < 64; off <<= 1) s8 += __shfl_xor(s8, off);
    float mu = s8 * (1.0f / 512.0f);
    float d0 = v0 - mu, d1 = v1 - mu, d2 = v2 - mu, d3 = v3 - mu;
    float d4 = v4 - mu, d5 = v5 - mu, d6 = v6 - mu, d7 = v7 - mu;
    float sq = d0 * d0 + d1 * d1 + d2 * d2 + d3 * d3 + d4 * d4 + d5 * d5 + d6 * d6 + d7 * d7;
#pragma unroll
    for (int off = 1; off < 64; off <<= 1) sq += __shfl_xor(sq, off);
    float rstd = rsqrtf(sq * (1.0f / 512.0f) + 1e-5f);
    float4 ga = *(const float4*)&g1[ch];
    float4 gb = *(const float4*)&g1[ch + 4];
    float4 ea = *(const float4*)&be1[ch];
    float4 eb = *(const float4*)&be1[ch + 4];
    float y0 = d0 * rstd * ga.x + ea.x, y1 = d1 * rstd * ga.y + ea.y;
    float y2 = d2 * rstd * ga.z + ea.z, y3 = d3 * rstd * ga.w + ea.w;
    float y4 = d4 * rstd * gb.x + eb.x, y5 = d5 * rstd * gb.y + eb.y;
    float y6 = d6 * rstd * gb.z + eb.z, y7 = d7 * rstd * gb.w + eb.w;
    y0 = (y0 > 0.f) ? y0 : (__expf(y0) - 1.0f);
    y1 = (y1 > 0.f) ? y1 : (__expf(y1) - 1.0f);
    y2 = (y2 > 0.f) ? y2 : (__expf(y2) - 1.0f);
    y3 = (y3 > 0.f) ? y3 : (__expf(y3) - 1.0f);
    y4 = (y4 > 0.f) ? y4 : (__expf(y4) - 1.0f);
    y5 = (y5 > 0.f) ? y5 : (__expf(y5) - 1.0f);
    y6 = (y6 > 0.f) ? y6 : (__expf(y6) - 1.0f);
    y7 = (y7 > 0.f) ? y7 : (__expf(y7) - 1.0f);
    uint4 o;
    o.x = (uint)f2h(y0) | ((uint)f2h(y1) << 16);
    o.y = (uint)f2h(y2) | ((uint)f2h(y3) << 16);
    o.z = (uint)f2h(y4) | ((uint)f2h(y5) << 16);
    o.w = (uint)f2h(y6) | ((uint)f2h(y7) << 16);
    *(uint4*)&h1h[(size_t)n * 512 + ch] = o;
}

// ---------------------------------------------------------------- layer-2 (R8): fused logits+softmax+alpha-out+gather+LN
__global__ __launch_bounds__(128) void k_agg2(const int* __restrict__ offsets, const int2* __restrict__ csr_se,
                                              const float* __restrict__ eattr, const float* __restrict__ loopattr,
                                              const float* __restrict__ als, const float* __restrict__ aldv,
                                              const float* __restrict__ m2v, const ushort* __restrict__ xh2h,
                                              const float* __restrict__ b2, const float* __restrict__ g2,
                                              const float* __restrict__ be2, float* __restrict__ eaout,
                                              ushort* __restrict__ h2h) {
    int wv = threadIdx.x >> 6, lane = threadIdx.x & 63;
    int n = blockIdx.x * 2 + wv;
    __shared__ float Lc[2][CAP];
    __shared__ int   sS[2][CAP];
    __shared__ int   sE[2][CAP];

    int start = offsets[n];
    int cnt = min(offsets[n + 1] - start, CAP);
    float aldn = aldv[n];
    float c0 = m2v[0], c1 = m2v[1], c2 = m2v[2], c3 = m2v[3];
    float m = -1e30f, s = 0.f;
    for (int j = lane; j < cnt; j += 64) {
        int2 se = csr_se[start + j];
        const float* eap = (se.y < N_EDGES) ? &eattr[(size_t)se.y * 4] : &loopattr[(size_t)(se.y - N_EDGES) * 4];
        float4 e4 = *(const float4*)eap;
        float l = als[se.x] + aldn + e4.x * c0 + e4.y * c1 + e4.z * c2 + e4.w * c3;
        l = (l >= 0.f) ? l : 0.2f * l;
        Lc[wv][j] = l; sS[wv][j] = se.x; sE[wv][j] = se.y;
        ONL(m, s, l);
    }
#pragma unroll
    for (int off = 1; off < 64; off <<= 1) { MRG(m, s, off); }
    float inv = 1.0f / s;
    for (int j = lane; j < cnt; j += 64) {
        float a = __expf(Lc[wv][j] - m) * inv;
        Lc[wv][j] = a;
        eaout[sE[wv][j]] = a;
    }
    // gather: lane owns channels 2*lane, 2*lane+1; 8 edges in flight; fp16 packed accumulate
    half2v hac = (half2v)0;
    uint ch = (uint)lane * 2u;
    int j = 0;
    for (; j + 8 <= cnt; j += 8) {
        _Float16 av[8];
        uint vv[8];
#pragma unroll
        for (int tt = 0; tt < 8; tt++) av[tt] = (_Float16)Lc[wv][j + tt];
#pragma unroll
        for (int tt = 0; tt < 8; tt++) vv[tt] = *(const uint*)&xh2h[((uint)sS[wv][j + tt] << 7) + ch];
#pragma unroll
        for (int tt = 0; tt < 8; tt++) {
            half2v a2 = (half2v){av[tt], av[tt]};
            half2v pv = __builtin_bit_cast(half2v, vv[tt]);
            hac = pv * a2 + hac;
        }
    }
    for (; j < cnt; j++) {
        _Float16 a = (_Float16)Lc[wv][j];
        half2v a2 = (half2v){a, a};
        half2v pv = __builtin_bit_cast(half2v, *(const uint*)&xh2h[((uint)sS[wv][j] << 7) + ch]);
        hac = pv * a2 + hac;
    }
    // bias + LN(128) within the wave
    float2 bb = *(const float2*)&b2[ch];
    float v0 = (float)hac[0] + bb.x, v1 = (float)hac[1] + bb.y;
    float s2 = v0 + v1;
#pragma unroll
    for (int off = 1; off < 64; off <<= 1) s2 += __shfl_xor(s2, off);
    float mu = s2 * (1.0f / 128.0f);
    float d0 = v0 - mu, d1 = v1 - mu;
    float q = d0 * d0 + d1 * d1;
#pragma unroll
    for (int off = 1; off < 64; off <<= 1) q += __shfl_xor(q, off);
    float rstd = rsqrtf(q * (1.0f / 128.0f) + 1e-5f);
    float2 gg = *(const float2*)&g2[ch];
    float2 ee = *(const float2*)&be2[ch];
    float y0 = d0 * rstd * gg.x + ee.x;
    float y1 = d1 * rstd * gg.y + ee.y;
    uint o = (uint)f2h(y0) | ((uint)f2h(y1) << 16);
    *(uint*)&h2h[(size_t)n * 128 + ch] = o;
}

// ================================================================ launch
extern "C" void kernel_launch(void* const* d_in, const int* in_sizes, int n_in,
                              void* d_out, int out_size, void* d_ws, size_t ws_size,
                              hipStream_t stream) {
    const float* x    = (const float*)d_in[0];
    const int*   eidx = (const int*)d_in[1];
    const float* eattr= (const float*)d_in[2];
    const float* Wp   = (const float*)d_in[3];
    const float* bp   = (const float*)d_in[4];
    const float* W1   = (const float*)d_in[5];
    const float* We1  = (const float*)d_in[6];
    const float* as1  = (const float*)d_in[7];
    const float* ad1  = (const float*)d_in[8];
    const float* ae1  = (const float*)d_in[9];
    const float* b1   = (const float*)d_in[10];
    const float* g1   = (const float*)d_in[11];
    const float* be1  = (const float*)d_in[12];
    const float* W2   = (const float*)d_in[13];
    const float* We2  = (const float*)d_in[14];
    const float* as2  = (const float*)d_in[15];
    const float* ad2  = (const float*)d_in[16];
    const float* ae2  = (const float*)d_in[17];
    const float* b2   = (const float*)d_in[18];
    const float* g2   = (const float*)d_in[19];
    const float* be2  = (const float*)d_in[20];
    const float* Wo   = (const float*)d_in[21];
    const float* bo   = (const float*)d_in[22];
    const float* Wi   = (const float*)d_in[23];
    const float* bi   = (const float*)d_in[24];

    const int* src = eidx;
    const int* dst = eidx + N_EDGES;

    float* emb_out = (float*)d_out;                       // [N,128]
    float* ea_out  = emb_out + (size_t)N_NODES * 128;     // [E+N]
    float* imp_out = ea_out + EN_TOT;                     // [N]

    // ---- workspace carve (256B aligned) ----
    char* w = (char*)d_ws;
    auto alloc = [&](size_t bytes) -> void* { void* p = (void*)w; w += (bytes + 255) & ~(size_t)255; return p; };
    ushort* xhh    = (ushort*)alloc((size_t)N_NODES * 512 * 2);  // [N,512] fp16
    ushort* h1h    = (ushort*)alloc((size_t)N_NODES * 512 * 2);  // [N,512] fp16
    ushort* h0h    = (ushort*)alloc((size_t)N_NODES * 128 * 2);  // [N,128] fp16
    ushort* xh2h   = (ushort*)alloc((size_t)N_NODES * 128 * 2);  // [N,128] fp16
    ushort* h2h    = (ushort*)alloc((size_t)N_NODES * 128 * 2);  // [N,128] fp16
    ushort* W1T    = (ushort*)alloc((size_t)512 * 128 * 2);
    ushort* W2T    = (ushort*)alloc((size_t)128 * 512 * 2);
    ushort* WoT    = (ushort*)alloc((size_t)128 * 128 * 2);
    int2*  csr_se  = (int2*)alloc((size_t)EN_TOT * 8);
    int*   offsets = (int*)alloc((size_t)(N_NODES + 1) * 4);
    int*   cursor  = (int*)alloc((size_t)N_NODES * 4);
    int*   degi    = (int*)alloc((size_t)N_NODES * 4);
    float* loopat  = (float*)alloc((size_t)N_NODES * 4 * 4);
    float* als1v   = (float*)alloc((size_t)N_NODES * 4 * 4);
    float* ald1v   = (float*)alloc((size_t)N_NODES * 4 * 4);
    float* als2v   = (float*)alloc((size_t)N_NODES * 4);
    float* ald2v   = (float*)alloc((size_t)N_NODES * 4);
    float* M1      = (float*)alloc(32 * 4);
    float* m2      = M1 + 16;

    hipMemsetAsync(degi,   0, (size_t)N_NODES * 4, stream);
    hipMemsetAsync(cursor, 0, (size_t)N_NODES * 4, stream);

    k_deg<<<(N_EDGES / 2 + 255) / 256, 256, 0, stream>>>(dst, degi);
    k_scan<<<1, 1024, 0, stream>>>(degi, offsets, We1, ae1, We2, ae2, M1, m2);
    k_fill<<<(EN_TOT + 255) / 256, 256, 0, stream>>>(src, dst, offsets, cursor, csr_se);
    k_misc<<<15576, 256, 0, stream>>>(offsets, csr_se, eattr, loopat, W1, W2, Wo,
                                      W1T, W2T, WoT, x, Wp, bp, h0h);

    // xh = h0 @ W1  + fused als1/ald1 (blockIdx.y == head)
    k_gemm_hf<64><<<dim3((N_NODES + 63) / 64, 4), 256, 0, stream>>>(h0h, W1T, nullptr, xhh,
                                                                    N_NODES, 512, 128, nullptr,
                                                                    as1, ad1, als1v, ald1v, 4, nullptr);
    k_agg1<<<N_NODES / 2, 128, 0, stream>>>(offsets, csr_se, eattr, loopat, als1v, ald1v, M1,
                                            xhh, b1, g1, be1, h1h);

    // xh2 = h1 @ W2  + fused als2/ald2  (BM=32 -> 625 blocks)
    k_gemm_hf<32><<<dim3((N_NODES + 31) / 32, 1), 256, 0, stream>>>(h1h, W2T, nullptr, xh2h,
                                                                    N_NODES, 128, 512, nullptr,
                                                                    as2, ad2, als2v, ald2v, 1, nullptr);
    k_agg2<<<N_NODES / 2, 128, 0, stream>>>(offsets, csr_se, eattr, loopat, als2v, ald2v, m2,
                                            xh2h, b2, g2, be2, ea_out, h2h);

    // emb = h2 @ Wo + bo -> d_out (fp32) + fused importance (sigmoid(emb@Wi+bi))
    k_gemm_hf<32><<<dim3((N_NODES + 31) / 32, 1), 256, 0, stream>>>(h2h, WoT, emb_out, nullptr,
                                                                    N_NODES, 128, 128, bo,
                                                                    Wi, nullptr, imp_out, nullptr, 1, bi);
}

// Round 13
// 194.988 us; speedup vs baseline: 2.6223x; 1.0371x over previous
//
#include <hip/hip_runtime.h>
#include <math.h>
#include <stdint.h>

#define N_NODES 20000
#define N_EDGES 320000
#define EN_TOT  340000   // E + N (with self loops)
#define CAP     160      // max per-node CSR segment (deg ~ Poisson(16); 160 is >30 sigma)

typedef __attribute__((ext_vector_type(8))) _Float16 half8v;  // 8 fp16 (4 VGPRs)
typedef __attribute__((ext_vector_type(2))) _Float16 half2v;  // packed fp16 pair
typedef __attribute__((ext_vector_type(4))) float float4v;    // MFMA accumulator

__device__ __forceinline__ ushort f2h(float f) {              // fp32 -> fp16 RNE
    _Float16 h = (_Float16)f;
    return __builtin_bit_cast(ushort, h);
}
__device__ __forceinline__ float h2f(ushort s) {
    return (float)__builtin_bit_cast(_Float16, s);
}

// online-softmax update / butterfly merge
#define ONL(mm, ss, ll) { float _mn = fmaxf(mm, ll); ss = ss * __expf(mm - _mn) + __expf(ll - _mn); mm = _mn; }
#define MRG(mm, ss, off) { float _mo = __shfl_xor(mm, off), _so = __shfl_xor(ss, off); \
                           float _mn = fmaxf(mm, _mo); ss = ss * __expf(mm - _mn) + _so * __expf(_mo - _mn); mm = _mn; }

// ---------------------------------------------------------------- degree count (1 int atomic / edge, int2 loads)
__global__ void k_deg(const int* __restrict__ dst, int* __restrict__ degi) {
    int e = (blockIdx.x * 256 + threadIdx.x) * 2;
    if (e >= N_EDGES) return;
    int2 d = *(const int2*)&dst[e];
    atomicAdd(&degi[d.x], 1);
    atomicAdd(&degi[d.y], 1);
}

// ---------------------------------------------------------------- scan (offsets) + M1/m2 fold
__global__ __launch_bounds__(1024) void k_scan(const int* __restrict__ degi, int* __restrict__ offsets,
                                               const float* __restrict__ We1, const float* __restrict__ ae1,
                                               const float* __restrict__ We2, const float* __restrict__ ae2,
                                               float* __restrict__ M1, float* __restrict__ m2) {
    __shared__ int s[1024];
    int t = threadIdx.x;
    int n0 = t * 20;
    int tot = 0;
    for (int i = 0; i < 20; i++) {
        int n = n0 + i;
        if (n < N_NODES) tot += degi[n] + 1;
    }
    s[t] = tot;
    __syncthreads();
    for (int off = 1; off < 1024; off <<= 1) {
        int v = (t >= off) ? s[t - off] : 0;
        __syncthreads();
        s[t] += v;
        __syncthreads();
    }
    int run = s[t] - tot;
    for (int i = 0; i < 20; i++) {
        int n = n0 + i;
        if (n < N_NODES) {
            offsets[n] = run;
            run += degi[n] + 1;
        }
    }
    if (t == 1023) offsets[N_NODES] = s[1023];
    if (t < 16) {
        int f = t >> 2, h = t & 3;
        float acc = 0.f;
        for (int c = 0; c < 128; c++) acc += We1[f * 512 + h * 128 + c] * ae1[h * 128 + c];
        M1[f * 4 + h] = acc;
    } else if (t < 20) {
        int f = t - 16;
        float acc = 0.f;
        for (int c = 0; c < 128; c++) acc += We2[f * 128 + c] * ae2[c];
        m2[f] = acc;
    }
}

// ---------------------------------------------------------------- CSR fill: self-contained int4 record {src, eid, ea01, ea23}
__global__ void k_fill(const int* __restrict__ src, const int* __restrict__ dst,
                       const float* __restrict__ eattr,
                       const int* __restrict__ offsets, int* __restrict__ cursor,
                       int4* __restrict__ csr) {
    int i = blockIdx.x * 256 + threadIdx.x;
    if (i >= EN_TOT) return;
    int d, sidx, eid;
    uint ea01 = 0, ea23 = 0;
    if (i < N_EDGES) {
        d = dst[i]; sidx = src[i]; eid = i;
        float4 e = *(const float4*)&eattr[(size_t)i * 4];
        ea01 = (uint)f2h(e.x) | ((uint)f2h(e.y) << 16);
        ea23 = (uint)f2h(e.z) | ((uint)f2h(e.w) << 16);
    } else {
        int n = i - N_EDGES; d = n; sidx = n; eid = N_EDGES + n;
        // ea filled later by k_misc (loop_attr mean)
    }
    int pos = offsets[d] + atomicAdd(&cursor[d], 1);
    csr[pos] = make_int4(sidx, eid, (int)ea01, (int)ea23);
}

// ---------------------------------------------------------------- merged: loop_attr->CSR self slot | weight prep | input proj
__global__ __launch_bounds__(256) void k_misc(const int* __restrict__ offsets, int4* __restrict__ csr,
                                              const float* __restrict__ W1, const float* __restrict__ W2,
                                              const float* __restrict__ Wo, ushort* __restrict__ W1T,
                                              ushort* __restrict__ W2T, ushort* __restrict__ WoT,
                                              const float* __restrict__ x, const float* __restrict__ Wp,
                                              const float* __restrict__ bp, ushort* __restrict__ h0h) {
    int b = blockIdx.x;
    int tid = threadIdx.x;
    if (b < 5000) {
        // loop_attr: mean of incoming (fp16-rounded) eattr -> write into self-loop record
        int wv = tid >> 6, l = tid & 63;
        int n = b * 4 + wv;
        if (n >= N_NODES) return;
        int start = offsets[n], end = offsets[n + 1];
        float sx = 0.f, sy = 0.f, sz = 0.f, sw = 0.f;
        int self = -1;
        for (int p = start + l; p < end; p += 64) {
            int4 r = csr[p];
            if (r.y < N_EDGES) {
                sx += h2f((ushort)((uint)r.z & 0xffffu));
                sy += h2f((ushort)((uint)r.z >> 16));
                sz += h2f((ushort)((uint)r.w & 0xffffu));
                sw += h2f((ushort)((uint)r.w >> 16));
            } else {
                self = p;
            }
        }
        for (int off = 32; off; off >>= 1) {
            sx += __shfl_down(sx, off);
            sy += __shfl_down(sy, off);
            sz += __shfl_down(sz, off);
            sw += __shfl_down(sw, off);
            self = max(self, __shfl_down(self, off));
        }
        if (l == 0) {
            float inv = 1.0f / fmaxf((float)(end - start - 1), 1.0f);
            uint ea01 = (uint)f2h(sx * inv) | ((uint)f2h(sy * inv) << 16);
            uint ea23 = (uint)f2h(sz * inv) | ((uint)f2h(sw * inv) << 16);
            csr[self].z = (int)ea01;
            csr[self].w = (int)ea23;
        }
    } else if (b < 5576) {
        int i = (b - 5000) * 256 + tid;
        if (i < 512 * 128) {
            int nn = i >> 7, kk = i & 127;
            W1T[i] = f2h(W1[kk * 512 + nn]);
        } else if (i < 2 * 512 * 128) {
            int j = i - 512 * 128;
            int nn = j >> 9, kk = j & 511;
            W2T[j] = f2h(W2[kk * 128 + nn]);
        } else if (i < 2 * 512 * 128 + 128 * 128) {
            int j = i - 2 * 512 * 128;
            int nn = j >> 7, kk = j & 127;
            WoT[j] = f2h(Wo[kk * 128 + nn]);
        }
    } else {
        int n = (b - 5576) * 2 + (tid >> 7);
        int c = tid & 127;
        float acc = bp[c];
#pragma unroll
        for (int f = 0; f < 4; f++) acc += x[n * 4 + f] * Wp[f * 128 + c];
        h0h[(size_t)n * 128 + c] = f2h(acc);
    }
}

// ---------------------------------------------------------------- MFMA fp16 GEMM + fused row-dot epilogue
// BM x 128 tile (BM = 64 or 32), BK=64, 4 waves each BM x 32, XOR-swizzled LDS.
template<int BM>
__global__ __launch_bounds__(256) void k_gemm_hf(const ushort* __restrict__ A, const ushort* __restrict__ BT,
                                                 float* __restrict__ Cf, ushort* __restrict__ Ch,
                                                 int M, int Nn, int K, const float* __restrict__ bias,
                                                 const float* __restrict__ asv, const float* __restrict__ adv,
                                                 float* __restrict__ outS, float* __restrict__ outD,
                                                 int hstride, const float* __restrict__ sbias) {
    constexpr int MR = BM / 16;
    __shared__ ushort As[BM * 64];
    __shared__ ushort Bs[128 * 64];
    __shared__ float redS[4][BM];
    __shared__ float redD[4][BM];
    const int tid = threadIdx.x;
    const int lane = tid & 63, wid = tid >> 6;
    const int m0 = blockIdx.x * BM, n0 = blockIdx.y * 128;
    float4v acc[MR][2];
#pragma unroll
    for (int i = 0; i < MR; i++)
#pragma unroll
        for (int j = 0; j < 2; j++) acc[i][j] = (float4v){0.f, 0.f, 0.f, 0.f};

    for (int k0 = 0; k0 < K; k0 += 64) {
        __syncthreads();
#pragma unroll
        for (int i = 0; i < BM * 8 / 256; i++) {       // A: BM rows x 8 chunks
            int c = tid + i * 256;
            int row = c >> 3, sl = c & 7;
            int off = row * 128 + ((sl ^ (row & 7)) << 4);
            uint4 va = make_uint4(0u, 0u, 0u, 0u);
            if (m0 + row < M) va = *(const uint4*)&A[(size_t)(m0 + row) * K + k0 + sl * 8];
            *(uint4*)((char*)As + off) = va;
        }
#pragma unroll
        for (int i = 0; i < 4; i++) {                  // B: 128 rows x 8 chunks
            int c = tid + i * 256;
            int row = c >> 3, sl = c & 7;
            int off = row * 128 + ((sl ^ (row & 7)) << 4);
            uint4 vb = *(const uint4*)&BT[(size_t)(n0 + row) * K + k0 + sl * 8];
            *(uint4*)((char*)Bs + off) = vb;
        }
        __syncthreads();
#pragma unroll
        for (int kk = 0; kk < 2; kk++) {
            half8v af[MR], bq[2];
            int sl = kk * 4 + (lane >> 4);
#pragma unroll
            for (int mi = 0; mi < MR; mi++) {
                int row = (lane & 15) + mi * 16;
                af[mi] = *(const half8v*)((const char*)As + row * 128 + ((sl ^ (row & 7)) << 4));
            }
#pragma unroll
            for (int ni = 0; ni < 2; ni++) {
                int row = wid * 32 + ni * 16 + (lane & 15);
                bq[ni] = *(const half8v*)((const char*)Bs + row * 128 + ((sl ^ (row & 7)) << 4));
            }
#pragma unroll
            for (int mi = 0; mi < MR; mi++)
#pragma unroll
                for (int ni = 0; ni < 2; ni++)
                    acc[mi][ni] = __builtin_amdgcn_mfma_f32_16x16x32_f16(af[mi], bq[ni], acc[mi][ni], 0, 0, 0);
        }
    }
    // ---- C write
    float bcol[2];
#pragma unroll
    for (int ni = 0; ni < 2; ni++)
        bcol[ni] = bias ? bias[n0 + wid * 32 + ni * 16 + (lane & 15)] : 0.f;
#pragma unroll
    for (int mi = 0; mi < MR; mi++) {
#pragma unroll
        for (int j = 0; j < 4; j++) {
            int row = m0 + mi * 16 + ((lane >> 4) << 2) + j;
            if (row < M) {
#pragma unroll
                for (int ni = 0; ni < 2; ni++) {
                    int col = n0 + wid * 32 + ni * 16 + (lane & 15);
                    float v = acc[mi][ni][j] + bcol[ni];
                    if (Cf) Cf[(size_t)row * Nn + col] = v;
                    if (Ch) Ch[(size_t)row * Nn + col] = f2h(v);
                }
            }
        }
    }
    // ---- fused row-dot epilogue (als/ald or sigmoid importance)
    if (asv) {
        float asl[2], adl[2];
#pragma unroll
        for (int ni = 0; ni < 2; ni++) {
            int col = n0 + wid * 32 + ni * 16 + (lane & 15);
            asl[ni] = asv[col];
            adl[ni] = adv ? adv[col] : 0.f;
        }
        float psv[MR][4], pdv[MR][4];
#pragma unroll
        for (int mi = 0; mi < MR; mi++)
#pragma unroll
            for (int j = 0; j < 4; j++) {
                float v0 = acc[mi][0][j] + bcol[0];
                float v1 = acc[mi][1][j] + bcol[1];
                psv[mi][j] = v0 * asl[0] + v1 * asl[1];
                pdv[mi][j] = v0 * adl[0] + v1 * adl[1];
            }
#pragma unroll
        for (int off = 1; off < 16; off <<= 1) {
#pragma unroll
            for (int mi = 0; mi < MR; mi++)
#pragma unroll
                for (int j = 0; j < 4; j++) {
                    psv[mi][j] += __shfl_xor(psv[mi][j], off);
                    pdv[mi][j] += __shfl_xor(pdv[mi][j], off);
                }
        }
        if ((lane & 15) == 0) {
#pragma unroll
            for (int mi = 0; mi < MR; mi++)
#pragma unroll
                for (int j = 0; j < 4; j++) {
                    int r = mi * 16 + ((lane >> 4) << 2) + j;
                    redS[wid][r] = psv[mi][j];
                    redD[wid][r] = pdv[mi][j];
                }
        }
        __syncthreads();
        if (tid < BM) {
            int row = m0 + tid;
            if (row < M) {
                float ss = redS[0][tid] + redS[1][tid] + redS[2][tid] + redS[3][tid];
                float dd = redD[0][tid] + redD[1][tid] + redD[2][tid] + redD[3][tid];
                if (sbias) {
                    outS[row] = 1.0f / (1.0f + __expf(-(ss + sbias[0])));
                } else {
                    outS[row * hstride + blockIdx.y] = ss;
                    if (outD) outD[row * hstride + blockIdx.y] = dd;
                }
            }
        }
    }
}

// ---------------------------------------------------------------- layer-1: fused logits+softmax+gather+LN+ELU
// 128 thr = 2 waves, ONE NODE PER WAVE, zero barriers. Self-contained CSR records (1 coalesced load / edge).
__global__ __launch_bounds__(128) void k_agg1(const int* __restrict__ offsets, const int4* __restrict__ csr,
                                              const float* __restrict__ als, const float* __restrict__ aldv,
                                              const float* __restrict__ M1, const ushort* __restrict__ xhh,
                                              const float* __restrict__ b1, const float* __restrict__ g1,
                                              const float* __restrict__ be1, ushort* __restrict__ h1h) {
    int wv = threadIdx.x >> 6, lane = threadIdx.x & 63;
    int n = blockIdx.x * 2 + wv;
    __shared__ float Lc[2][CAP][4];
    __shared__ int   sSrc[2][CAP];
    __shared__ float mhs[2][4], shs[2][4];

    int start = offsets[n];
    int cnt = min(offsets[n + 1] - start, CAP);
    const int4* seg = &csr[start];

    // ---- phase A: inline logits + online softmax stats (4 lanes per edge)
    int hh = lane & 3;
    float aldn = aldv[n * 4 + hh];
    float c0 = M1[hh], c1 = M1[4 + hh], c2 = M1[8 + hh], c3 = M1[12 + hh];
    float m = -1e30f, s = 0.f;
    for (int j = lane >> 2; j < cnt; j += 16) {
        int4 r = seg[j];
        float e0 = h2f((ushort)((uint)r.z & 0xffffu));
        float e1 = h2f((ushort)((uint)r.z >> 16));
        float e2 = h2f((ushort)((uint)r.w & 0xffffu));
        float e3 = h2f((ushort)((uint)r.w >> 16));
        float l = als[r.x * 4 + hh] + aldn + e0 * c0 + e1 * c1 + e2 * c2 + e3 * c3;
        l = (l >= 0.f) ? l : 0.2f * l;
        Lc[wv][j][hh] = l;
        if (hh == 0) sSrc[wv][j] = r.x;
        ONL(m, s, l);
    }
#pragma unroll
    for (int off = 4; off < 64; off <<= 1) { MRG(m, s, off); }
    if (lane < 4) { mhs[wv][lane] = m; shs[wv][lane] = 1.0f / s; }
    // wave-internal LDS ordering: no barrier needed (per-wave slices)

    // ---- phase A2: logits -> alpha in place
    int tot = cnt * 4;
    for (int idx = lane; idx < tot; idx += 64) {
        int j = idx >> 2, h = idx & 3;
        Lc[wv][j][h] = __expf(Lc[wv][j][h] - mhs[wv][h]) * shs[wv][h];
    }

    // ---- gather: lane owns channels 8*lane..8*lane+7; 8 edges in flight; fp16 packed accumulate
    half2v hac0 = (half2v)0, hac1 = (half2v)0, hac2 = (half2v)0, hac3 = (half2v)0;
    int hg = lane >> 4;
    uint ch = (uint)lane * 8u;
    int j = 0;
    for (; j + 8 <= cnt; j += 8) {
        _Float16 av[8];
        uint4 vv[8];
#pragma unroll
        for (int t = 0; t < 8; t++) av[t] = (_Float16)Lc[wv][j + t][hg];
#pragma unroll
        for (int t = 0; t < 8; t++) vv[t] = *(const uint4*)&xhh[((uint)sSrc[wv][j + t] << 9) + ch];
#pragma unroll
        for (int t = 0; t < 8; t++) {
            half2v a2 = (half2v){av[t], av[t]};
            const half2v* pv = (const half2v*)&vv[t];
            hac0 = pv[0] * a2 + hac0;
            hac1 = pv[1] * a2 + hac1;
            hac2 = pv[2] * a2 + hac2;
            hac3 = pv[3] * a2 + hac3;
        }
    }
    for (; j < cnt; j++) {
        _Float16 a = (_Float16)Lc[wv][j][hg];
        half2v a2 = (half2v){a, a};
        uint4 v = *(const uint4*)&xhh[((uint)sSrc[wv][j] << 9) + ch];
        const half2v* pv = (const half2v*)&v;
        hac0 = pv[0] * a2 + hac0;
        hac1 = pv[1] * a2 + hac1;
        hac2 = pv[2] * a2 + hac2;
        hac3 = pv[3] * a2 + hac3;
    }

    // ---- + bias, LayerNorm(512), ELU — wave-local shuffles
    float4 ba = *(const float4*)&b1[ch];
    float4 bb = *(const float4*)&b1[ch + 4];
    float v0 = (float)hac0[0] + ba.x, v1 = (float)hac0[1] + ba.y;
    float v2 = (float)hac1[0] + ba.z, v3 = (float)hac1[1] + ba.w;
    float v4 = (float)hac2[0] + bb.x, v5 = (float)hac2[1] + bb.y;
    float v6 = (float)hac3[0] + bb.z, v7 = (float)hac3[1] + bb.w;
    float s8 = v0 + v1 + v2 + v3 + v4 + v5 + v6 + v7;
#pragma unroll
    for (int off = 1; off < 64; off <<= 1) s8 += __shfl_xor(s8, off);
    float mu = s8 * (1.0f / 512.0f);
    float d0 = v0 - mu, d1 = v1 - mu, d2 = v2 - mu, d3 = v3 - mu;
    float d4 = v4 - mu, d5 = v5 - mu, d6 = v6 - mu, d7 = v7 - mu;
    float sq = d0 * d0 + d1 * d1 + d2 * d2 + d3 * d3 + d4 * d4 + d5 * d5 + d6 * d6 + d7 * d7;
#pragma unroll
    for (int off = 1; off < 64; off <<= 1) sq += __shfl_xor(sq, off);
    float rstd = rsqrtf(sq * (1.0f / 512.0f) + 1e-5f);
    float4 ga = *(const float4*)&g1[ch];
    float4 gb = *(const float4*)&g1[ch + 4];
    float4 ea = *(const float4*)&be1[ch];
    float4 eb = *(const float4*)&be1[ch + 4];
    float y0 = d0 * rstd * ga.x + ea.x, y1 = d1 * rstd * ga.y + ea.y;
    float y2 = d2 * rstd * ga.z + ea.z, y3 = d3 * rstd * ga.w + ea.w;
    float y4 = d4 * rstd * gb.x + eb.x, y5 = d5 * rstd * gb.y + eb.y;
    float y6 = d6 * rstd * gb.z + eb.z, y7 = d7 * rstd * gb.w + eb.w;
    y0 = (y0 > 0.f) ? y0 : (__expf(y0) - 1.0f);
    y1 = (y1 > 0.f) ? y1 : (__expf(y1) - 1.0f);
    y2 = (y2 > 0.f) ? y2 : (__expf(y2) - 1.0f);
    y3 = (y3 > 0.f) ? y3 : (__expf(y3) - 1.0f);
    y4 = (y4 > 0.f) ? y4 : (__expf(y4) - 1.0f);
    y5 = (y5 > 0.f) ? y5 : (__expf(y5) - 1.0f);
    y6 = (y6 > 0.f) ? y6 : (__expf(y6) - 1.0f);
    y7 = (y7 > 0.f) ? y7 : (__expf(y7) - 1.0f);
    uint4 o;
    o.x = (uint)f2h(y0) | ((uint)f2h(y1) << 16);
    o.y = (uint)f2h(y2) | ((uint)f2h(y3) << 16);
    o.z = (uint)f2h(y4) | ((uint)f2h(y5) << 16);
    o.w = (uint)f2h(y6) | ((uint)f2h(y7) << 16);
    *(uint4*)&h1h[(size_t)n * 512 + ch] = o;
}

// ---------------------------------------------------------------- layer-2: fused logits+softmax+alpha-out+gather+LN
// 128 thr = 2 waves, ONE NODE PER WAVE, zero barriers. Self-contained CSR records.
__global__ __launch_bounds__(128) void k_agg2(const int* __restrict__ offsets, const int4* __restrict__ csr,
                                              const float* __restrict__ als, const float* __restrict__ aldv,
                                              const float* __restrict__ m2v, const ushort* __restrict__ xh2h,
                                              const float* __restrict__ b2, const float* __restrict__ g2,
                                              const float* __restrict__ be2, float* __restrict__ eaout,
                                              ushort* __restrict__ h2h) {
    int wv = threadIdx.x >> 6, lane = threadIdx.x & 63;
    int n = blockIdx.x * 2 + wv;
    __shared__ float Lc[2][CAP];
    __shared__ int   sS[2][CAP];

    int start = offsets[n];
    int cnt = min(offsets[n + 1] - start, CAP);
    const int4* seg = &csr[start];
    float aldn = aldv[n];
    float c0 = m2v[0], c1 = m2v[1], c2 = m2v[2], c3 = m2v[3];
    float m = -1e30f, s = 0.f;
    for (int j = lane; j < cnt; j += 64) {
        int4 r = seg[j];
        float e0 = h2f((ushort)((uint)r.z & 0xffffu));
        float e1 = h2f((ushort)((uint)r.z >> 16));
        float e2 = h2f((ushort)((uint)r.w & 0xffffu));
        float e3 = h2f((ushort)((uint)r.w >> 16));
        float l = als[r.x] + aldn + e0 * c0 + e1 * c1 + e2 * c2 + e3 * c3;
        l = (l >= 0.f) ? l : 0.2f * l;
        Lc[wv][j] = l; sS[wv][j] = r.x;
        ONL(m, s, l);
    }
#pragma unroll
    for (int off = 1; off < 64; off <<= 1) { MRG(m, s, off); }
    float inv = 1.0f / s;
    for (int j = lane; j < cnt; j += 64) {
        float a = __expf(Lc[wv][j] - m) * inv;
        Lc[wv][j] = a;
        eaout[seg[j].y] = a;     // L1/L2-hot reload of record for eid
    }
    // gather: lane owns channels 2*lane, 2*lane+1; 8 edges in flight; fp16 packed accumulate
    half2v hac = (half2v)0;
    uint ch = (uint)lane * 2u;
    int j = 0;
    for (; j + 8 <= cnt; j += 8) {
        _Float16 av[8];
        uint vv[8];
#pragma unroll
        for (int tt = 0; tt < 8; tt++) av[tt] = (_Float16)Lc[wv][j + tt];
#pragma unroll
        for (int tt = 0; tt < 8; tt++) vv[tt] = *(const uint*)&xh2h[((uint)sS[wv][j + tt] << 7) + ch];
#pragma unroll
        for (int tt = 0; tt < 8; tt++) {
            half2v a2 = (half2v){av[tt], av[tt]};
            half2v pv = __builtin_bit_cast(half2v, vv[tt]);
            hac = pv * a2 + hac;
        }
    }
    for (; j < cnt; j++) {
        _Float16 a = (_Float16)Lc[wv][j];
        half2v a2 = (half2v){a, a};
        half2v pv = __builtin_bit_cast(half2v, *(const uint*)&xh2h[((uint)sS[wv][j] << 7) + ch]);
        hac = pv * a2 + hac;
    }
    // bias + LN(128) within the wave
    float2 bb = *(const float2*)&b2[ch];
    float v0 = (float)hac[0] + bb.x, v1 = (float)hac[1] + bb.y;
    float s2 = v0 + v1;
#pragma unroll
    for (int off = 1; off < 64; off <<= 1) s2 += __shfl_xor(s2, off);
    float mu = s2 * (1.0f / 128.0f);
    float d0 = v0 - mu, d1 = v1 - mu;
    float q = d0 * d0 + d1 * d1;
#pragma unroll
    for (int off = 1; off < 64; off <<= 1) q += __shfl_xor(q, off);
    float rstd = rsqrtf(q * (1.0f / 128.0f) + 1e-5f);
    float2 gg = *(const float2*)&g2[ch];
    float2 ee = *(const float2*)&be2[ch];
    float y0 = d0 * rstd * gg.x + ee.x;
    float y1 = d1 * rstd * gg.y + ee.y;
    uint o = (uint)f2h(y0) | ((uint)f2h(y1) << 16);
    *(uint*)&h2h[(size_t)n * 128 + ch] = o;
}

// ================================================================ launch
extern "C" void kernel_launch(void* const* d_in, const int* in_sizes, int n_in,
                              void* d_out, int out_size, void* d_ws, size_t ws_size,
                              hipStream_t stream) {
    const float* x    = (const float*)d_in[0];
    const int*   eidx = (const int*)d_in[1];
    const float* eattr= (const float*)d_in[2];
    const float* Wp   = (const float*)d_in[3];
    const float* bp   = (const float*)d_in[4];
    const float* W1   = (const float*)d_in[5];
    const float* We1  = (const float*)d_in[6];
    const float* as1  = (const float*)d_in[7];
    const float* ad1  = (const float*)d_in[8];
    const float* ae1  = (const float*)d_in[9];
    const float* b1   = (const float*)d_in[10];
    const float* g1   = (const float*)d_in[11];
    const float* be1  = (const float*)d_in[12];
    const float* W2   = (const float*)d_in[13];
    const float* We2  = (const float*)d_in[14];
    const float* as2  = (const float*)d_in[15];
    const float* ad2  = (const float*)d_in[16];
    const float* ae2  = (const float*)d_in[17];
    const float* b2   = (const float*)d_in[18];
    const float* g2   = (const float*)d_in[19];
    const float* be2  = (const float*)d_in[20];
    const float* Wo   = (const float*)d_in[21];
    const float* bo   = (const float*)d_in[22];
    const float* Wi   = (const float*)d_in[23];
    const float* bi   = (const float*)d_in[24];

    const int* src = eidx;
    const int* dst = eidx + N_EDGES;

    float* emb_out = (float*)d_out;                       // [N,128]
    float* ea_out  = emb_out + (size_t)N_NODES * 128;     // [E+N]
    float* imp_out = ea_out + EN_TOT;                     // [N]

    // ---- workspace carve (256B aligned) ----
    char* w = (char*)d_ws;
    auto alloc = [&](size_t bytes) -> void* { void* p = (void*)w; w += (bytes + 255) & ~(size_t)255; return p; };
    ushort* xhh    = (ushort*)alloc((size_t)N_NODES * 512 * 2);  // [N,512] fp16
    ushort* h1h    = (ushort*)alloc((size_t)N_NODES * 512 * 2);  // [N,512] fp16
    ushort* h0h    = (ushort*)alloc((size_t)N_NODES * 128 * 2);  // [N,128] fp16
    ushort* xh2h   = (ushort*)alloc((size_t)N_NODES * 128 * 2);  // [N,128] fp16
    ushort* h2h    = (ushort*)alloc((size_t)N_NODES * 128 * 2);  // [N,128] fp16
    ushort* W1T    = (ushort*)alloc((size_t)512 * 128 * 2);
    ushort* W2T    = (ushort*)alloc((size_t)128 * 512 * 2);
    ushort* WoT    = (ushort*)alloc((size_t)128 * 128 * 2);
    int4*  csr     = (int4*)alloc((size_t)EN_TOT * 16);
    int*   offsets = (int*)alloc((size_t)(N_NODES + 1) * 4);
    int*   cursor  = (int*)alloc((size_t)N_NODES * 4);
    int*   degi    = (int*)alloc((size_t)N_NODES * 4);
    float* als1v   = (float*)alloc((size_t)N_NODES * 4 * 4);
    float* ald1v   = (float*)alloc((size_t)N_NODES * 4 * 4);
    float* als2v   = (float*)alloc((size_t)N_NODES * 4);
    float* ald2v   = (float*)alloc((size_t)N_NODES * 4);
    float* M1      = (float*)alloc(32 * 4);
    float* m2      = M1 + 16;

    hipMemsetAsync(degi,   0, (size_t)N_NODES * 4, stream);
    hipMemsetAsync(cursor, 0, (size_t)N_NODES * 4, stream);

    k_deg<<<(N_EDGES / 2 + 255) / 256, 256, 0, stream>>>(dst, degi);
    k_scan<<<1, 1024, 0, stream>>>(degi, offsets, We1, ae1, We2, ae2, M1, m2);
    k_fill<<<(EN_TOT + 255) / 256, 256, 0, stream>>>(src, dst, eattr, offsets, cursor, csr);
    k_misc<<<15576, 256, 0, stream>>>(offsets, csr, W1, W2, Wo,
                                      W1T, W2T, WoT, x, Wp, bp, h0h);

    // xh = h0 @ W1  + fused als1/ald1 (blockIdx.y == head)
    k_gemm_hf<64><<<dim3((N_NODES + 63) / 64, 4), 256, 0, stream>>>(h0h, W1T, nullptr, xhh,
                                                                    N_NODES, 512, 128, nullptr,
                                                                    as1, ad1, als1v, ald1v, 4, nullptr);
    k_agg1<<<N_NODES / 2, 128, 0, stream>>>(offsets, csr, als1v, ald1v, M1,
                                            xhh, b1, g1, be1, h1h);

    // xh2 = h1 @ W2  + fused als2/ald2  (BM=32 -> 625 blocks)
    k_gemm_hf<32><<<dim3((N_NODES + 31) / 32, 1), 256, 0, stream>>>(h1h, W2T, nullptr, xh2h,
                                                                    N_NODES, 128, 512, nullptr,
                                                                    as2, ad2, als2v, ald2v, 1, nullptr);
    k_agg2<<<N_NODES / 2, 128, 0, stream>>>(offsets, csr, als2v, ald2v, m2,
                                            xh2h, b2, g2, be2, ea_out, h2h);

    // emb = h2 @ Wo + bo -> d_out (fp32) + fused importance (sigmoid(emb@Wi+bi))
    k_gemm_hf<32><<<dim3((N_NODES + 31) / 32, 1), 256, 0, stream>>>(h2h, WoT, emb_out, nullptr,
                                                                    N_NODES, 128, 128, bo,
                                                                    Wi, nullptr, imp_out, nullptr, 1, bi);
}

// Round 14
// 192.626 us; speedup vs baseline: 2.6545x; 1.0123x over previous
//
#include <hip/hip_runtime.h>
#include <math.h>
#include <stdint.h>

#define N_NODES 20000
#define N_EDGES 320000
#define EN_TOT  340000   // E + N (with self loops)
#define CAP     160      // max per-node CSR segment (deg ~ Poisson(16); 160 is >30 sigma)

typedef __attribute__((ext_vector_type(8))) _Float16 half8v;  // 8 fp16 (4 VGPRs)
typedef __attribute__((ext_vector_type(2))) _Float16 half2v;  // packed fp16 pair
typedef __attribute__((ext_vector_type(4))) float float4v;    // MFMA accumulator

__device__ __forceinline__ ushort f2h(float f) {              // fp32 -> fp16 RNE
    _Float16 h = (_Float16)f;
    return __builtin_bit_cast(ushort, h);
}
__device__ __forceinline__ float h2f(ushort s) {
    return (float)__builtin_bit_cast(_Float16, s);
}

// online-softmax update / butterfly merge
#define ONL(mm, ss, ll) { float _mn = fmaxf(mm, ll); ss = ss * __expf(mm - _mn) + __expf(ll - _mn); mm = _mn; }
#define MRG(mm, ss, off) { float _mo = __shfl_xor(mm, off), _so = __shfl_xor(ss, off); \
                           float _mn = fmaxf(mm, _mo); ss = ss * __expf(mm - _mn) + _so * __expf(_mo - _mn); mm = _mn; }

// ---------------------------------------------------------------- degree count (1 int atomic / edge, int2 loads)
__global__ void k_deg(const int* __restrict__ dst, int* __restrict__ degi) {
    int e = (blockIdx.x * 256 + threadIdx.x) * 2;
    if (e >= N_EDGES) return;
    int2 d = *(const int2*)&dst[e];
    atomicAdd(&degi[d.x], 1);
    atomicAdd(&degi[d.y], 1);
}

// ---------------------------------------------------------------- scan (offsets) + M1/m2 fold
__global__ __launch_bounds__(1024) void k_scan(const int* __restrict__ degi, int* __restrict__ offsets,
                                               const float* __restrict__ We1, const float* __restrict__ ae1,
                                               const float* __restrict__ We2, const float* __restrict__ ae2,
                                               float* __restrict__ M1, float* __restrict__ m2) {
    __shared__ int s[1024];
    int t = threadIdx.x;
    int n0 = t * 20;
    int tot = 0;
    for (int i = 0; i < 20; i++) {
        int n = n0 + i;
        if (n < N_NODES) tot += degi[n] + 1;
    }
    s[t] = tot;
    __syncthreads();
    for (int off = 1; off < 1024; off <<= 1) {
        int v = (t >= off) ? s[t - off] : 0;
        __syncthreads();
        s[t] += v;
        __syncthreads();
    }
    int run = s[t] - tot;
    for (int i = 0; i < 20; i++) {
        int n = n0 + i;
        if (n < N_NODES) {
            offsets[n] = run;
            run += degi[n] + 1;
        }
    }
    if (t == 1023) offsets[N_NODES] = s[1023];
    if (t < 16) {
        int f = t >> 2, h = t & 3;
        float acc = 0.f;
        for (int c = 0; c < 128; c++) acc += We1[f * 512 + h * 128 + c] * ae1[h * 128 + c];
        M1[f * 4 + h] = acc;
    } else if (t < 20) {
        int f = t - 16;
        float acc = 0.f;
        for (int c = 0; c < 128; c++) acc += We2[f * 128 + c] * ae2[c];
        m2[f] = acc;
    }
}

// ---------------------------------------------------------------- CSR fill: self-contained int4 record {src, eid, ea01, ea23}
__global__ void k_fill(const int* __restrict__ src, const int* __restrict__ dst,
                       const float* __restrict__ eattr,
                       const int* __restrict__ offsets, int* __restrict__ cursor,
                       int4* __restrict__ csr) {
    int i = blockIdx.x * 256 + threadIdx.x;
    if (i >= EN_TOT) return;
    int d, sidx, eid;
    uint ea01 = 0, ea23 = 0;
    if (i < N_EDGES) {
        d = dst[i]; sidx = src[i]; eid = i;
        float4 e = *(const float4*)&eattr[(size_t)i * 4];
        ea01 = (uint)f2h(e.x) | ((uint)f2h(e.y) << 16);
        ea23 = (uint)f2h(e.z) | ((uint)f2h(e.w) << 16);
    } else {
        int n = i - N_EDGES; d = n; sidx = n; eid = N_EDGES + n;
        // ea filled later by k_misc (loop_attr mean)
    }
    int pos = offsets[d] + atomicAdd(&cursor[d], 1);
    csr[pos] = make_int4(sidx, eid, (int)ea01, (int)ea23);
}

// ---------------------------------------------------------------- merged: loop_attr->CSR self slot | weight prep
__global__ __launch_bounds__(256) void k_misc(const int* __restrict__ offsets, int4* __restrict__ csr,
                                              const float* __restrict__ W1, const float* __restrict__ W2,
                                              const float* __restrict__ Wo, ushort* __restrict__ W1T,
                                              ushort* __restrict__ W2T, ushort* __restrict__ WoT) {
    int b = blockIdx.x;
    int tid = threadIdx.x;
    if (b < 5000) {
        // loop_attr: mean of incoming (fp16-rounded) eattr -> write into self-loop record
        int wv = tid >> 6, l = tid & 63;
        int n = b * 4 + wv;
        if (n >= N_NODES) return;
        int start = offsets[n], end = offsets[n + 1];
        float sx = 0.f, sy = 0.f, sz = 0.f, sw = 0.f;
        int self = -1;
        for (int p = start + l; p < end; p += 64) {
            int4 r = csr[p];
            if (r.y < N_EDGES) {
                sx += h2f((ushort)((uint)r.z & 0xffffu));
                sy += h2f((ushort)((uint)r.z >> 16));
                sz += h2f((ushort)((uint)r.w & 0xffffu));
                sw += h2f((ushort)((uint)r.w >> 16));
            } else {
                self = p;
            }
        }
        for (int off = 32; off; off >>= 1) {
            sx += __shfl_down(sx, off);
            sy += __shfl_down(sy, off);
            sz += __shfl_down(sz, off);
            sw += __shfl_down(sw, off);
            self = max(self, __shfl_down(self, off));
        }
        if (l == 0) {
            float inv = 1.0f / fmaxf((float)(end - start - 1), 1.0f);
            uint ea01 = (uint)f2h(sx * inv) | ((uint)f2h(sy * inv) << 16);
            uint ea23 = (uint)f2h(sz * inv) | ((uint)f2h(sw * inv) << 16);
            csr[self].z = (int)ea01;
            csr[self].w = (int)ea23;
        }
    } else {
        int i = (b - 5000) * 256 + tid;
        if (i < 512 * 128) {
            int nn = i >> 7, kk = i & 127;
            W1T[i] = f2h(W1[kk * 512 + nn]);
        } else if (i < 2 * 512 * 128) {
            int j = i - 512 * 128;
            int nn = j >> 9, kk = j & 511;
            W2T[j] = f2h(W2[kk * 128 + nn]);
        } else if (i < 2 * 512 * 128 + 128 * 128) {
            int j = i - 2 * 512 * 128;
            int nn = j >> 7, kk = j & 127;
            WoT[j] = f2h(Wo[kk * 128 + nn]);
        }
    }
}

// ---------------------------------------------------------------- MFMA fp16 GEMM + fused row-dot epilogue
// BM x 128 tile, BK=64, 4 waves each BM x 32, XOR-swizzled LDS.
// PROJ: A computed on the fly as h0 = x @ Wp + bp (fp16-rounded, bitwise = staged version).
template<int BM, bool PROJ>
__global__ __launch_bounds__(256) void k_gemm_hf(const ushort* __restrict__ A, const ushort* __restrict__ BT,
                                                 float* __restrict__ Cf, ushort* __restrict__ Ch,
                                                 int M, int Nn, int K, const float* __restrict__ bias,
                                                 const float* __restrict__ asv, const float* __restrict__ adv,
                                                 float* __restrict__ outS, float* __restrict__ outD,
                                                 int hstride, const float* __restrict__ sbias,
                                                 const float* __restrict__ Xf, const float* __restrict__ Wpf,
                                                 const float* __restrict__ bpf) {
    constexpr int MR = BM / 16;
    __shared__ ushort As[BM * 64];
    __shared__ ushort Bs[128 * 64];
    __shared__ float redS[4][BM];
    __shared__ float redD[4][BM];
    const int tid = threadIdx.x;
    const int lane = tid & 63, wid = tid >> 6;
    const int m0 = blockIdx.x * BM, n0 = blockIdx.y * 128;
    float4v acc[MR][2];
#pragma unroll
    for (int i = 0; i < MR; i++)
#pragma unroll
        for (int j = 0; j < 2; j++) acc[i][j] = (float4v){0.f, 0.f, 0.f, 0.f};

    for (int k0 = 0; k0 < K; k0 += 64) {
        __syncthreads();
#pragma unroll
        for (int i = 0; i < BM * 8 / 256; i++) {       // A: BM rows x 8 chunks
            int c = tid + i * 256;
            int row = c >> 3, sl = c & 7;
            int off = row * 128 + ((sl ^ (row & 7)) << 4);
            uint4 va = make_uint4(0u, 0u, 0u, 0u);
            if (m0 + row < M) {
                if (PROJ) {
                    float4 xr = *(const float4*)&Xf[(size_t)(m0 + row) * 4];
                    ushort h[8];
#pragma unroll
                    for (int q = 0; q < 8; q++) {
                        int col = k0 + sl * 8 + q;
                        float a = bpf[col] + xr.x * Wpf[col] + xr.y * Wpf[128 + col]
                                + xr.z * Wpf[256 + col] + xr.w * Wpf[384 + col];
                        h[q] = f2h(a);
                    }
                    va.x = (uint)h[0] | ((uint)h[1] << 16);
                    va.y = (uint)h[2] | ((uint)h[3] << 16);
                    va.z = (uint)h[4] | ((uint)h[5] << 16);
                    va.w = (uint)h[6] | ((uint)h[7] << 16);
                } else {
                    va = *(const uint4*)&A[(size_t)(m0 + row) * K + k0 + sl * 8];
                }
            }
            *(uint4*)((char*)As + off) = va;
        }
#pragma unroll
        for (int i = 0; i < 4; i++) {                  // B: 128 rows x 8 chunks
            int c = tid + i * 256;
            int row = c >> 3, sl = c & 7;
            int off = row * 128 + ((sl ^ (row & 7)) << 4);
            uint4 vb = *(const uint4*)&BT[(size_t)(n0 + row) * K + k0 + sl * 8];
            *(uint4*)((char*)Bs + off) = vb;
        }
        __syncthreads();
#pragma unroll
        for (int kk = 0; kk < 2; kk++) {
            half8v af[MR], bq[2];
            int sl = kk * 4 + (lane >> 4);
#pragma unroll
            for (int mi = 0; mi < MR; mi++) {
                int row = (lane & 15) + mi * 16;
                af[mi] = *(const half8v*)((const char*)As + row * 128 + ((sl ^ (row & 7)) << 4));
            }
#pragma unroll
            for (int ni = 0; ni < 2; ni++) {
                int row = wid * 32 + ni * 16 + (lane & 15);
                bq[ni] = *(const half8v*)((const char*)Bs + row * 128 + ((sl ^ (row & 7)) << 4));
            }
#pragma unroll
            for (int mi = 0; mi < MR; mi++)
#pragma unroll
                for (int ni = 0; ni < 2; ni++)
                    acc[mi][ni] = __builtin_amdgcn_mfma_f32_16x16x32_f16(af[mi], bq[ni], acc[mi][ni], 0, 0, 0);
        }
    }
    // ---- C write
    float bcol[2];
#pragma unroll
    for (int ni = 0; ni < 2; ni++)
        bcol[ni] = bias ? bias[n0 + wid * 32 + ni * 16 + (lane & 15)] : 0.f;
#pragma unroll
    for (int mi = 0; mi < MR; mi++) {
#pragma unroll
        for (int j = 0; j < 4; j++) {
            int row = m0 + mi * 16 + ((lane >> 4) << 2) + j;
            if (row < M) {
#pragma unroll
                for (int ni = 0; ni < 2; ni++) {
                    int col = n0 + wid * 32 + ni * 16 + (lane & 15);
                    float v = acc[mi][ni][j] + bcol[ni];
                    if (Cf) Cf[(size_t)row * Nn + col] = v;
                    if (Ch) Ch[(size_t)row * Nn + col] = f2h(v);
                }
            }
        }
    }
    // ---- fused row-dot epilogue (als/ald or sigmoid importance)
    if (asv) {
        float asl[2], adl[2];
#pragma unroll
        for (int ni = 0; ni < 2; ni++) {
            int col = n0 + wid * 32 + ni * 16 + (lane & 15);
            asl[ni] = asv[col];
            adl[ni] = adv ? adv[col] : 0.f;
        }
        float psv[MR][4], pdv[MR][4];
#pragma unroll
        for (int mi = 0; mi < MR; mi++)
#pragma unroll
            for (int j = 0; j < 4; j++) {
                float v0 = acc[mi][0][j] + bcol[0];
                float v1 = acc[mi][1][j] + bcol[1];
                psv[mi][j] = v0 * asl[0] + v1 * asl[1];
                pdv[mi][j] = v0 * adl[0] + v1 * adl[1];
            }
#pragma unroll
        for (int off = 1; off < 16; off <<= 1) {
#pragma unroll
            for (int mi = 0; mi < MR; mi++)
#pragma unroll
                for (int j = 0; j < 4; j++) {
                    psv[mi][j] += __shfl_xor(psv[mi][j], off);
                    pdv[mi][j] += __shfl_xor(pdv[mi][j], off);
                }
        }
        if ((lane & 15) == 0) {
#pragma unroll
            for (int mi = 0; mi < MR; mi++)
#pragma unroll
                for (int j = 0; j < 4; j++) {
                    int r = mi * 16 + ((lane >> 4) << 2) + j;
                    redS[wid][r] = psv[mi][j];
                    redD[wid][r] = pdv[mi][j];
                }
        }
        __syncthreads();
        if (tid < BM) {
            int row = m0 + tid;
            if (row < M) {
                float ss = redS[0][tid] + redS[1][tid] + redS[2][tid] + redS[3][tid];
                float dd = redD[0][tid] + redD[1][tid] + redD[2][tid] + redD[3][tid];
                if (sbias) {
                    outS[row] = 1.0f / (1.0f + __expf(-(ss + sbias[0])));
                } else {
                    outS[row * hstride + blockIdx.y] = ss;
                    if (outD) outD[row * hstride + blockIdx.y] = dd;
                }
            }
        }
    }
}

// ---------------------------------------------------------------- layer-1: fused logits+softmax+gather+LN+ELU
// 128 thr = 2 waves, ONE NODE PER WAVE, zero barriers. Self-contained CSR records (1 coalesced load / edge).
__global__ __launch_bounds__(128) void k_agg1(const int* __restrict__ offsets, const int4* __restrict__ csr,
                                              const float* __restrict__ als, const float* __restrict__ aldv,
                                              const float* __restrict__ M1, const ushort* __restrict__ xhh,
                                              const float* __restrict__ b1, const float* __restrict__ g1,
                                              const float* __restrict__ be1, ushort* __restrict__ h1h) {
    int wv = threadIdx.x >> 6, lane = threadIdx.x & 63;
    int n = blockIdx.x * 2 + wv;
    __shared__ float Lc[2][CAP][4];
    __shared__ int   sSrc[2][CAP];
    __shared__ float mhs[2][4], shs[2][4];

    int start = offsets[n];
    int cnt = min(offsets[n + 1] - start, CAP);
    const int4* seg = &csr[start];

    // ---- phase A: inline logits + online softmax stats (4 lanes per edge)
    int hh = lane & 3;
    float aldn = aldv[n * 4 + hh];
    float c0 = M1[hh], c1 = M1[4 + hh], c2 = M1[8 + hh], c3 = M1[12 + hh];
    float m = -1e30f, s = 0.f;
    for (int j = lane >> 2; j < cnt; j += 16) {
        int4 r = seg[j];
        float e0 = h2f((ushort)((uint)r.z & 0xffffu));
        float e1 = h2f((ushort)((uint)r.z >> 16));
        float e2 = h2f((ushort)((uint)r.w & 0xffffu));
        float e3 = h2f((ushort)((uint)r.w >> 16));
        float l = als[r.x * 4 + hh] + aldn + e0 * c0 + e1 * c1 + e2 * c2 + e3 * c3;
        l = (l >= 0.f) ? l : 0.2f * l;
        Lc[wv][j][hh] = l;
        if (hh == 0) sSrc[wv][j] = r.x;
        ONL(m, s, l);
    }
#pragma unroll
    for (int off = 4; off < 64; off <<= 1) { MRG(m, s, off); }
    if (lane < 4) { mhs[wv][lane] = m; shs[wv][lane] = 1.0f / s; }
    // wave-internal LDS ordering: no barrier needed (per-wave slices)

    // ---- phase A2: logits -> alpha in place
    int tot = cnt * 4;
    for (int idx = lane; idx < tot; idx += 64) {
        int j = idx >> 2, h = idx & 3;
        Lc[wv][j][h] = __expf(Lc[wv][j][h] - mhs[wv][h]) * shs[wv][h];
    }

    // ---- gather: lane owns channels 8*lane..8*lane+7; 8 edges in flight; fp16 packed accumulate
    half2v hac0 = (half2v)0, hac1 = (half2v)0, hac2 = (half2v)0, hac3 = (half2v)0;
    int hg = lane >> 4;
    uint ch = (uint)lane * 8u;
    int j = 0;
    for (; j + 8 <= cnt; j += 8) {
        _Float16 av[8];
        uint4 vv[8];
#pragma unroll
        for (int t = 0; t < 8; t++) av[t] = (_Float16)Lc[wv][j + t][hg];
#pragma unroll
        for (int t = 0; t < 8; t++) vv[t] = *(const uint4*)&xhh[((uint)sSrc[wv][j + t] << 9) + ch];
#pragma unroll
        for (int t = 0; t < 8; t++) {
            half2v a2 = (half2v){av[t], av[t]};
            const half2v* pv = (const half2v*)&vv[t];
            hac0 = pv[0] * a2 + hac0;
            hac1 = pv[1] * a2 + hac1;
            hac2 = pv[2] * a2 + hac2;
            hac3 = pv[3] * a2 + hac3;
        }
    }
    for (; j < cnt; j++) {
        _Float16 a = (_Float16)Lc[wv][j][hg];
        half2v a2 = (half2v){a, a};
        uint4 v = *(const uint4*)&xhh[((uint)sSrc[wv][j] << 9) + ch];
        const half2v* pv = (const half2v*)&v;
        hac0 = pv[0] * a2 + hac0;
        hac1 = pv[1] * a2 + hac1;
        hac2 = pv[2] * a2 + hac2;
        hac3 = pv[3] * a2 + hac3;
    }

    // ---- + bias, LayerNorm(512), ELU — wave-local shuffles
    float4 ba = *(const float4*)&b1[ch];
    float4 bb = *(const float4*)&b1[ch + 4];
    float v0 = (float)hac0[0] + ba.x, v1 = (float)hac0[1] + ba.y;
    float v2 = (float)hac1[0] + ba.z, v3 = (float)hac1[1] + ba.w;
    float v4 = (float)hac2[0] + bb.x, v5 = (float)hac2[1] + bb.y;
    float v6 = (float)hac3[0] + bb.z, v7 = (float)hac3[1] + bb.w;
    float s8 = v0 + v1 + v2 + v3 + v4 + v5 + v6 + v7;
#pragma unroll
    for (int off = 1; off < 64; off <<= 1) s8 += __shfl_xor(s8, off);
    float mu = s8 * (1.0f / 512.0f);
    float d0 = v0 - mu, d1 = v1 - mu, d2 = v2 - mu, d3 = v3 - mu;
    float d4 = v4 - mu, d5 = v5 - mu, d6 = v6 - mu, d7 = v7 - mu;
    float sq = d0 * d0 + d1 * d1 + d2 * d2 + d3 * d3 + d4 * d4 + d5 * d5 + d6 * d6 + d7 * d7;
#pragma unroll
    for (int off = 1; off < 64; off <<= 1) sq += __shfl_xor(sq, off);
    float rstd = rsqrtf(sq * (1.0f / 512.0f) + 1e-5f);
    float4 ga = *(const float4*)&g1[ch];
    float4 gb = *(const float4*)&g1[ch + 4];
    float4 ea = *(const float4*)&be1[ch];
    float4 eb = *(const float4*)&be1[ch + 4];
    float y0 = d0 * rstd * ga.x + ea.x, y1 = d1 * rstd * ga.y + ea.y;
    float y2 = d2 * rstd * ga.z + ea.z, y3 = d3 * rstd * ga.w + ea.w;
    float y4 = d4 * rstd * gb.x + eb.x, y5 = d5 * rstd * gb.y + eb.y;
    float y6 = d6 * rstd * gb.z + eb.z, y7 = d7 * rstd * gb.w + eb.w;
    y0 = (y0 > 0.f) ? y0 : (__expf(y0) - 1.0f);
    y1 = (y1 > 0.f) ? y1 : (__expf(y1) - 1.0f);
    y2 = (y2 > 0.f) ? y2 : (__expf(y2) - 1.0f);
    y3 = (y3 > 0.f) ? y3 : (__expf(y3) - 1.0f);
    y4 = (y4 > 0.f) ? y4 : (__expf(y4) - 1.0f);
    y5 = (y5 > 0.f) ? y5 : (__expf(y5) - 1.0f);
    y6 = (y6 > 0.f) ? y6 : (__expf(y6) - 1.0f);
    y7 = (y7 > 0.f) ? y7 : (__expf(y7) - 1.0f);
    uint4 o;
    o.x = (uint)f2h(y0) | ((uint)f2h(y1) << 16);
    o.y = (uint)f2h(y2) | ((uint)f2h(y3) << 16);
    o.z = (uint)f2h(y4) | ((uint)f2h(y5) << 16);
    o.w = (uint)f2h(y6) | ((uint)f2h(y7) << 16);
    *(uint4*)&h1h[(size_t)n * 512 + ch] = o;
}

// ---------------------------------------------------------------- layer-2: fused logits+softmax+alpha-out+gather+LN
// 128 thr = 2 waves, ONE NODE PER WAVE, zero barriers. Self-contained CSR records.
__global__ __launch_bounds__(128) void k_agg2(const int* __restrict__ offsets, const int4* __restrict__ csr,
                                              const float* __restrict__ als, const float* __restrict__ aldv,
                                              const float* __restrict__ m2v, const ushort* __restrict__ xh2h,
                                              const float* __restrict__ b2, const float* __restrict__ g2,
                                              const float* __restrict__ be2, float* __restrict__ eaout,
                                              ushort* __restrict__ h2h) {
    int wv = threadIdx.x >> 6, lane = threadIdx.x & 63;
    int n = blockIdx.x * 2 + wv;
    __shared__ float Lc[2][CAP];
    __shared__ int   sS[2][CAP];

    int start = offsets[n];
    int cnt = min(offsets[n + 1] - start, CAP);
    const int4* seg = &csr[start];
    float aldn = aldv[n];
    float c0 = m2v[0], c1 = m2v[1], c2 = m2v[2], c3 = m2v[3];
    float m = -1e30f, s = 0.f;
    for (int j = lane; j < cnt; j += 64) {
        int4 r = seg[j];
        float e0 = h2f((ushort)((uint)r.z & 0xffffu));
        float e1 = h2f((ushort)((uint)r.z >> 16));
        float e2 = h2f((ushort)((uint)r.w & 0xffffu));
        float e3 = h2f((ushort)((uint)r.w >> 16));
        float l = als[r.x] + aldn + e0 * c0 + e1 * c1 + e2 * c2 + e3 * c3;
        l = (l >= 0.f) ? l : 0.2f * l;
        Lc[wv][j] = l; sS[wv][j] = r.x;
        ONL(m, s, l);
    }
#pragma unroll
    for (int off = 1; off < 64; off <<= 1) { MRG(m, s, off); }
    float inv = 1.0f / s;
    for (int j = lane; j < cnt; j += 64) {
        float a = __expf(Lc[wv][j] - m) * inv;
        Lc[wv][j] = a;
        eaout[seg[j].y] = a;     // L1/L2-hot reload of record for eid
    }
    // gather: lane owns channels 2*lane, 2*lane+1; 8 edges in flight; fp16 packed accumulate
    half2v hac = (half2v)0;
    uint ch = (uint)lane * 2u;
    int j = 0;
    for (; j + 8 <= cnt; j += 8) {
        _Float16 av[8];
        uint vv[8];
#pragma unroll
        for (int tt = 0; tt < 8; tt++) av[tt] = (_Float16)Lc[wv][j + tt];
#pragma unroll
        for (int tt = 0; tt < 8; tt++) vv[tt] = *(const uint*)&xh2h[((uint)sS[wv][j + tt] << 7) + ch];
#pragma unroll
        for (int tt = 0; tt < 8; tt++) {
            half2v a2 = (half2v){av[tt], av[tt]};
            half2v pv = __builtin_bit_cast(half2v, vv[tt]);
            hac = pv * a2 + hac;
        }
    }
    for (; j < cnt; j++) {
        _Float16 a = (_Float16)Lc[wv][j];
        half2v a2 = (half2v){a, a};
        half2v pv = __builtin_bit_cast(half2v, *(const uint*)&xh2h[((uint)sS[wv][j] << 7) + ch]);
        hac = pv * a2 + hac;
    }
    // bias + LN(128) within the wave
    float2 bb = *(const float2*)&b2[ch];
    float v0 = (float)hac[0] + bb.x, v1 = (float)hac[1] + bb.y;
    float s2 = v0 + v1;
#pragma unroll
    for (int off = 1; off < 64; off <<= 1) s2 += __shfl_xor(s2, off);
    float mu = s2 * (1.0f / 128.0f);
    float d0 = v0 - mu, d1 = v1 - mu;
    float q = d0 * d0 + d1 * d1;
#pragma unroll
    for (int off = 1; off < 64; off <<= 1) q += __shfl_xor(q, off);
    float rstd = rsqrtf(q * (1.0f / 128.0f) + 1e-5f);
    float2 gg = *(const float2*)&g2[ch];
    float2 ee = *(const float2*)&be2[ch];
    float y0 = d0 * rstd * gg.x + ee.x;
    float y1 = d1 * rstd * gg.y + ee.y;
    uint o = (uint)f2h(y0) | ((uint)f2h(y1) << 16);
    *(uint*)&h2h[(size_t)n * 128 + ch] = o;
}

// ================================================================ launch
extern "C" void kernel_launch(void* const* d_in, const int* in_sizes, int n_in,
                              void* d_out, int out_size, void* d_ws, size_t ws_size,
                              hipStream_t stream) {
    const float* x    = (const float*)d_in[0];
    const int*   eidx = (const int*)d_in[1];
    const float* eattr= (const float*)d_in[2];
    const float* Wp   = (const float*)d_in[3];
    const float* bp   = (const float*)d_in[4];
    const float* W1   = (const float*)d_in[5];
    const float* We1  = (const float*)d_in[6];
    const float* as1  = (const float*)d_in[7];
    const float* ad1  = (const float*)d_in[8];
    const float* ae1  = (const float*)d_in[9];
    const float* b1   = (const float*)d_in[10];
    const float* g1   = (const float*)d_in[11];
    const float* be1  = (const float*)d_in[12];
    const float* W2   = (const float*)d_in[13];
    const float* We2  = (const float*)d_in[14];
    const float* as2  = (const float*)d_in[15];
    const float* ad2  = (const float*)d_in[16];
    const float* ae2  = (const float*)d_in[17];
    const float* b2   = (const float*)d_in[18];
    const float* g2   = (const float*)d_in[19];
    const float* be2  = (const float*)d_in[20];
    const float* Wo   = (const float*)d_in[21];
    const float* bo   = (const float*)d_in[22];
    const float* Wi   = (const float*)d_in[23];
    const float* bi   = (const float*)d_in[24];

    const int* src = eidx;
    const int* dst = eidx + N_EDGES;

    float* emb_out = (float*)d_out;                       // [N,128]
    float* ea_out  = emb_out + (size_t)N_NODES * 128;     // [E+N]
    float* imp_out = ea_out + EN_TOT;                     // [N]

    // ---- workspace carve (256B aligned) ----
    char* w = (char*)d_ws;
    auto alloc = [&](size_t bytes) -> void* { void* p = (void*)w; w += (bytes + 255) & ~(size_t)255; return p; };
    ushort* xhh    = (ushort*)alloc((size_t)N_NODES * 512 * 2);  // [N,512] fp16
    ushort* h1h    = (ushort*)alloc((size_t)N_NODES * 512 * 2);  // [N,512] fp16
    ushort* xh2h   = (ushort*)alloc((size_t)N_NODES * 128 * 2);  // [N,128] fp16
    ushort* h2h    = (ushort*)alloc((size_t)N_NODES * 128 * 2);  // [N,128] fp16
    ushort* W1T    = (ushort*)alloc((size_t)512 * 128 * 2);
    ushort* W2T    = (ushort*)alloc((size_t)128 * 512 * 2);
    ushort* WoT    = (ushort*)alloc((size_t)128 * 128 * 2);
    int4*  csr     = (int4*)alloc((size_t)EN_TOT * 16);
    int*   offsets = (int*)alloc((size_t)(N_NODES + 1) * 4);
    int*   degi    = (int*)alloc((size_t)N_NODES * 4);    // degi+cursor adjacent: single memset
    int*   cursor  = (int*)alloc((size_t)N_NODES * 4);
    float* als1v   = (float*)alloc((size_t)N_NODES * 4 * 4);
    float* ald1v   = (float*)alloc((size_t)N_NODES * 4 * 4);
    float* als2v   = (float*)alloc((size_t)N_NODES * 4);
    float* ald2v   = (float*)alloc((size_t)N_NODES * 4);
    float* M1      = (float*)alloc(32 * 4);
    float* m2      = M1 + 16;

    hipMemsetAsync(degi, 0, (size_t)((char*)cursor - (char*)degi) + (size_t)N_NODES * 4, stream);

    k_deg<<<(N_EDGES / 2 + 255) / 256, 256, 0, stream>>>(dst, degi);
    k_scan<<<1, 1024, 0, stream>>>(degi, offsets, We1, ae1, We2, ae2, M1, m2);
    k_fill<<<(EN_TOT + 255) / 256, 256, 0, stream>>>(src, dst, eattr, offsets, cursor, csr);
    k_misc<<<5576, 256, 0, stream>>>(offsets, csr, W1, W2, Wo, W1T, W2T, WoT);

    // xh = (x@Wp+bp) @ W1  (PROJ on-the-fly A) + fused als1/ald1 (blockIdx.y == head)
    k_gemm_hf<64, true><<<dim3((N_NODES + 63) / 64, 4), 256, 0, stream>>>(
        nullptr, W1T, nullptr, xhh, N_NODES, 512, 128, nullptr,
        as1, ad1, als1v, ald1v, 4, nullptr, x, Wp, bp);
    k_agg1<<<N_NODES / 2, 128, 0, stream>>>(offsets, csr, als1v, ald1v, M1,
                                            xhh, b1, g1, be1, h1h);

    // xh2 = h1 @ W2  + fused als2/ald2  (BM=32 -> 625 blocks)
    k_gemm_hf<32, false><<<dim3((N_NODES + 31) / 32, 1), 256, 0, stream>>>(
        h1h, W2T, nullptr, xh2h, N_NODES, 128, 512, nullptr,
        as2, ad2, als2v, ald2v, 1, nullptr, nullptr, nullptr, nullptr);
    k_agg2<<<N_NODES / 2, 128, 0, stream>>>(offsets, csr, als2v, ald2v, m2,
                                            xh2h, b2, g2, be2, ea_out, h2h);

    // emb = h2 @ Wo + bo -> d_out (fp32) + fused importance (sigmoid(emb@Wi+bi))
    k_gemm_hf<32, false><<<dim3((N_NODES + 31) / 32, 1), 256, 0, stream>>>(
        h2h, WoT, emb_out, nullptr, N_NODES, 128, 128, bo,
        Wi, nullptr, imp_out, nullptr, 1, bi, nullptr, nullptr, nullptr);
}